// Round 2
// baseline (1025.406 us; speedup 1.0000x reference)
//
#include <hip/hip_runtime.h>
#include <math.h>
#include <float.h>
#include <limits.h>

#define N 8192
#define D 64
#define TOPK 32
#define TILE 128
#define CAP 1024       // fallback path: per-wave LDS candidate cap
#define CAPC 1024      // sampled path: per-row global candidate cap
#define MS 1024        // number of sampled columns (every 8th)
#define SSTRIDE 8      // column sampling stride

// orderable-uint encoding of float: a > b  <=>  ford(a) > ford(b)
__device__ __forceinline__ unsigned ford(float f) {
    unsigned u = __float_as_uint(f);
    return u ^ ((u & 0x80000000u) ? 0xFFFFFFFFu : 0x80000000u);
}
__device__ __forceinline__ float finv(unsigned u) {
    unsigned b = (u & 0x80000000u) ? (u ^ 0x80000000u) : ~u;
    return __uint_as_float(b);
}

// ---------------------------------------------------------------------------
// Kernel 1: row norms of X1 and X2 -> nrm[0..2N)
// ---------------------------------------------------------------------------
__global__ __launch_bounds__(256) void norms_kernel(
    const float* __restrict__ X1, const float* __restrict__ X2,
    float* __restrict__ nrm)
{
    int id = blockIdx.x * blockDim.x + threadIdx.x;
    if (id >= 2 * N) return;
    const float* X = (id < N) ? X1 : X2;
    int r = (id < N) ? id : id - N;
    const float4* p = (const float4*)(X + (size_t)r * D);
    float s = 0.f;
#pragma unroll
    for (int q = 0; q < D / 4; ++q) {
        float4 v = p[q];
        s += v.x * v.x + v.y * v.y + v.z * v.z + v.w * v.w;
    }
    nrm[id] = s;
}

// ---------------------------------------------------------------------------
// Kernel 2 (sampled path): 1/8-cost GEMM over X1 x X2[every 8th col].
// Writes exact v = -max(sq,0) for 8192 x 1024 sampled pairs to Sm.
// Proven 128x128 tile / 8x8 micro-tile / XOR swizzle.
// ---------------------------------------------------------------------------
__global__ __launch_bounds__(256, 2) void samp_gemm_kernel(
    const float* __restrict__ X1, const float* __restrict__ X2,
    const float* __restrict__ nrm, float* __restrict__ Sm)
{
    __shared__ float As[D * TILE];
    __shared__ float Bs[D * TILE];

    const int t = threadIdx.x;
    const int row0 = blockIdx.y * TILE;
    const int col0 = blockIdx.x * TILE;   // sampled-column base

#pragma unroll
    for (int p = 0; p < 8; ++p) {
        int lin = p * 256 + t;
        int r   = lin >> 4;
        int d4  = (lin & 15) << 2;
        int g   = (d4 >> 2) & 7;
        int cb  = r ^ (g << 3);
        float4 a = *(const float4*)(X1 + (size_t)(row0 + r) * D + d4);
        As[(d4 + 0) * TILE + cb] = a.x;
        As[(d4 + 1) * TILE + cb] = a.y;
        As[(d4 + 2) * TILE + cb] = a.z;
        As[(d4 + 3) * TILE + cb] = a.w;
        // sampled column (col0+r) -> actual X2 row (col0+r)*SSTRIDE
        float4 b = *(const float4*)(X2 + (size_t)(col0 + r) * SSTRIDE * D + d4);
        Bs[(d4 + 0) * TILE + cb] = b.x;
        Bs[(d4 + 1) * TILE + cb] = b.y;
        Bs[(d4 + 2) * TILE + cb] = b.z;
        Bs[(d4 + 3) * TILE + cb] = b.w;
    }
    __syncthreads();

    const int tx = t & 15;
    const int ty = t >> 4;
    float acc[8][8] = {};

#pragma unroll 8
    for (int k = 0; k < D; ++k) {
        int gk  = (k >> 2) & 7;
        int ab  = k * TILE + ((ty ^ gk) << 3);
        int bb0 = k * TILE + ((4 * tx) ^ (gk << 3));
        float4 a0 = *(const float4*)&As[ab];
        float4 a1 = *(const float4*)&As[ab + 4];
        float4 b0 = *(const float4*)&Bs[bb0];
        float4 b1 = *(const float4*)&Bs[bb0 + 64];
        float av[8] = {a0.x, a0.y, a0.z, a0.w, a1.x, a1.y, a1.z, a1.w};
        float bv[8] = {b0.x, b0.y, b0.z, b0.w, b1.x, b1.y, b1.z, b1.w};
#pragma unroll
        for (int i = 0; i < 8; ++i)
#pragma unroll
            for (int j = 0; j < 8; ++j)
                acc[i][j] += av[i] * bv[j];
    }

    float na[8], nb[8];
#pragma unroll
    for (int i = 0; i < 8; ++i) na[i] = nrm[row0 + 8 * ty + i];
#pragma unroll
    for (int q = 0; q < 4; ++q) {
        nb[q]     = nrm[N + (size_t)(col0 + 4 * tx + q) * SSTRIDE];
        nb[4 + q] = nrm[N + (size_t)(col0 + 64 + 4 * tx + q) * SSTRIDE];
    }

#pragma unroll
    for (int i = 0; i < 8; ++i) {
        float* po = Sm + (size_t)(row0 + 8 * ty + i) * MS + col0 + 4 * tx;
        float4 o0, o1;
        float* f0 = (float*)&o0;
        float* f1 = (float*)&o1;
#pragma unroll
        for (int q = 0; q < 4; ++q) {
            float s0 = na[i] + nb[q] - 2.0f * acc[i][q];
            f0[q] = -fmaxf(s0, 0.0f);
            float s1 = na[i] + nb[4 + q] - 2.0f * acc[i][4 + q];
            f1[q] = -fmaxf(s1, 0.0f);
        }
        *(float4*)po        = o0;
        *(float4*)(po + 64) = o1;
    }
}

// ---------------------------------------------------------------------------
// Kernel 3 (sampled path): per row, 32nd-largest of the 1024 sampled values
// (exact, via 32x wave-argmax with invalidation) minus 1e-3 margin -> thr.
// Sound: subset 32nd-largest <= full 32nd-largest. Also zeroes cnt[row].
// ---------------------------------------------------------------------------
__global__ __launch_bounds__(256) void samp_thr_kernel(
    const float* __restrict__ Sm, float* __restrict__ thr,
    int* __restrict__ cnt)
{
    __shared__ unsigned long long skey[4][MS];   // 32 KB
    const int t = threadIdx.x;
    const int w = t >> 6;
    const int lane = t & 63;
    const int r = blockIdx.x * 4 + w;

    const float4* sr = (const float4*)(Sm + (size_t)r * MS);
#pragma unroll
    for (int c = 0; c < 4; ++c) {
        float4 x = sr[c * 64 + lane];
        float vs[4] = {x.x, x.y, x.z, x.w};
#pragma unroll
        for (int q = 0; q < 4; ++q) {
            int slot = 4 * (c * 64 + lane) + q;
            skey[w][slot] = ((unsigned long long)ford(vs[q]) << 32) | (unsigned)slot;
        }
    }
    __builtin_amdgcn_s_waitcnt(0xC07F);   // lgkmcnt(0)

    unsigned long long b0 = 0ull;
    for (int it = 0; it < TOPK; ++it) {
        unsigned long long b = 0ull; int bp = 0;
#pragma unroll
        for (int c = 0; c < MS / 64; ++c) {
            int q = c * 64 + lane;
            unsigned long long kk = skey[w][q];
            if (kk > b) { b = kk; bp = q; }
        }
        for (int off = 32; off > 0; off >>= 1) {
            unsigned long long ob = __shfl_down(b, off);
            int op = __shfl_down(bp, off);
            if (ob > b) { b = ob; bp = op; }
        }
        b0 = __shfl(b, 0);
        int bp0 = __shfl(bp, 0);
        if (lane == 0) skey[w][bp0] = 0ull;
        __builtin_amdgcn_s_waitcnt(0xC07F);
    }
    // b0 is now the 32nd-largest sampled value's key
    if (lane == 0) {
        thr[r] = finv((unsigned)(b0 >> 32)) - 1e-3f;  // margin for accum-order diff
        cnt[r] = 0;
    }
}

// ---------------------------------------------------------------------------
// Kernel 4 (sampled path): the single full GEMM. Original 4096-block tile
// structure (one 128x128 tile per block -> block-level pipelining restored).
// Epilogue: write ZEROS to out, append survivors (v >= thr[row]) to the
// per-row global candidate buffer (~256/row expected, cap 1024).
// ---------------------------------------------------------------------------
__global__ __launch_bounds__(256, 2) void cand_zero_kernel(
    const float* __restrict__ X1, const float* __restrict__ X2,
    const float* __restrict__ nrm, const float* __restrict__ thr,
    float* __restrict__ out, unsigned long long* __restrict__ cand,
    int* __restrict__ cnt)
{
    __shared__ float As[D * TILE];
    __shared__ float Bs[D * TILE];

    const int t = threadIdx.x;
    const int row0 = blockIdx.y * TILE;
    const int col0 = blockIdx.x * TILE;

#pragma unroll
    for (int p = 0; p < 8; ++p) {
        int lin = p * 256 + t;
        int r   = lin >> 4;
        int d4  = (lin & 15) << 2;
        int g   = (d4 >> 2) & 7;
        int cb  = r ^ (g << 3);
        float4 a = *(const float4*)(X1 + (size_t)(row0 + r) * D + d4);
        As[(d4 + 0) * TILE + cb] = a.x;
        As[(d4 + 1) * TILE + cb] = a.y;
        As[(d4 + 2) * TILE + cb] = a.z;
        As[(d4 + 3) * TILE + cb] = a.w;
        float4 b = *(const float4*)(X2 + (size_t)(col0 + r) * D + d4);
        Bs[(d4 + 0) * TILE + cb] = b.x;
        Bs[(d4 + 1) * TILE + cb] = b.y;
        Bs[(d4 + 2) * TILE + cb] = b.z;
        Bs[(d4 + 3) * TILE + cb] = b.w;
    }
    __syncthreads();

    const int tx = t & 15;
    const int ty = t >> 4;
    float acc[8][8] = {};

#pragma unroll 8
    for (int k = 0; k < D; ++k) {
        int gk  = (k >> 2) & 7;
        int ab  = k * TILE + ((ty ^ gk) << 3);
        int bb0 = k * TILE + ((4 * tx) ^ (gk << 3));
        float4 a0 = *(const float4*)&As[ab];
        float4 a1 = *(const float4*)&As[ab + 4];
        float4 b0 = *(const float4*)&Bs[bb0];
        float4 b1 = *(const float4*)&Bs[bb0 + 64];
        float av[8] = {a0.x, a0.y, a0.z, a0.w, a1.x, a1.y, a1.z, a1.w};
        float bv[8] = {b0.x, b0.y, b0.z, b0.w, b1.x, b1.y, b1.z, b1.w};
#pragma unroll
        for (int i = 0; i < 8; ++i)
#pragma unroll
            for (int j = 0; j < 8; ++j)
                acc[i][j] += av[i] * bv[j];
    }

    float na[8], nb[8], thv[8];
#pragma unroll
    for (int i = 0; i < 8; ++i) {
        na[i]  = nrm[row0 + 8 * ty + i];
        thv[i] = thr[row0 + 8 * ty + i];
    }
#pragma unroll
    for (int q = 0; q < 4; ++q) {
        nb[q]     = nrm[N + col0 + 4 * tx + q];
        nb[4 + q] = nrm[N + col0 + 64 + 4 * tx + q];
    }

    const float4 zz = make_float4(0.f, 0.f, 0.f, 0.f);
#pragma unroll
    for (int i = 0; i < 8; ++i) {
        const int row = row0 + 8 * ty + i;
        float* po = out + (size_t)row * N + col0 + 4 * tx;
        *(float4*)po        = zz;       // zero stores independent of acc: issue early
        *(float4*)(po + 64) = zz;
#pragma unroll
        for (int q = 0; q < 8; ++q) {
            float s = na[i] + nb[q] - 2.0f * acc[i][q];
            float v = -fmaxf(s, 0.0f);
            if (v >= thv[i]) {
                int col = col0 + ((q < 4) ? (4 * tx + q) : (64 + 4 * tx + (q - 4)));
                int p0 = atomicAdd(&cnt[row], 1);
                if (p0 < CAPC)
                    cand[(size_t)row * CAPC + p0] =
                        ((unsigned long long)ford(v) << 32) |
                        (unsigned)(8191 - col);
            }
        }
    }
}

// ---------------------------------------------------------------------------
// Kernel 5 (sampled path): one wave per row; exact top-32 from <=CAPC
// candidates, sqrt + softmax, scatter over the zeros written by kernel 4.
// ---------------------------------------------------------------------------
__global__ __launch_bounds__(256) void topk_scatter_kernel(
    float* __restrict__ out, float* __restrict__ score_out,
    const unsigned long long* __restrict__ cand, const int* __restrict__ cnt)
{
    __shared__ unsigned long long cs[4][CAPC];   // 32 KB
    const int t = threadIdx.x;
    const int w = t >> 6;
    const int lane = t & 63;
    const int r = blockIdx.x * 4 + w;

    int n = cnt[r];
    if (n > CAPC) n = CAPC;
    const unsigned long long* cr = cand + (size_t)r * CAPC;
    for (int q = lane; q < n; q += 64) cs[w][q] = cr[q];
    __builtin_amdgcn_s_waitcnt(0xC07F);   // lgkmcnt(0)

    unsigned long long mykey = 0ull;
    for (int it = 0; it < TOPK; ++it) {
        unsigned long long b = 0ull; int bp = 0;
        for (int q = lane; q < n; q += 64) {
            unsigned long long kk = cs[w][q];
            if (kk > b) { b = kk; bp = q; }
        }
        for (int off = 32; off > 0; off >>= 1) {
            unsigned long long ob = __shfl_down(b, off);
            int op = __shfl_down(bp, off);
            if (ob > b) { b = ob; bp = op; }
        }
        unsigned long long b0 = __shfl(b, 0);
        int bp0 = __shfl(bp, 0);
        if (lane == it) { mykey = b0; cs[w][bp0] = 0ull; }
    }

    float myv = 0.f; int myj = 0;
    if (lane < TOPK) {
        float sv = finv((unsigned)(mykey >> 32));   // stored -max(sq,0)
        myv = -sqrtf(-sv);
        myj = 8191 - (int)(mykey & 0xFFFFFFFFu);
    }
    float Mx = __shfl(myv, 0);
    float e = (lane < TOPK) ? expf(myv - Mx) : 0.f;
    float Z = e;
    for (int off = 32; off > 0; off >>= 1) Z += __shfl_xor(Z, off);
    float s = e / Z;
    if (lane < TOPK) {
        score_out[(size_t)r * TOPK + lane] = s;
        out[(size_t)r * N + myj] = s;    // zeros already laid down by kernel 4
    }
}

// ---------------------------------------------------------------------------
// FALLBACK path (workspace too small): r0 verified pipeline.
// ---------------------------------------------------------------------------
__global__ __launch_bounds__(256, 2) void dist_kernel(
    const float* __restrict__ X1, const float* __restrict__ X2,
    const float* __restrict__ nrm, float* __restrict__ out,
    float* __restrict__ tmax, int have_tmax)
{
    __shared__ float As[D * TILE];
    __shared__ float Bs[D * TILE];

    const int t = threadIdx.x;
    const int row0 = blockIdx.y * TILE;
    const int col0 = blockIdx.x * TILE;

#pragma unroll
    for (int p = 0; p < 8; ++p) {
        int lin = p * 256 + t;
        int r   = lin >> 4;
        int d4  = (lin & 15) << 2;
        int g   = (d4 >> 2) & 7;
        int cb  = r ^ (g << 3);
        float4 a = *(const float4*)(X1 + (size_t)(row0 + r) * D + d4);
        As[(d4 + 0) * TILE + cb] = a.x;
        As[(d4 + 1) * TILE + cb] = a.y;
        As[(d4 + 2) * TILE + cb] = a.z;
        As[(d4 + 3) * TILE + cb] = a.w;
        float4 b = *(const float4*)(X2 + (size_t)(col0 + r) * D + d4);
        Bs[(d4 + 0) * TILE + cb] = b.x;
        Bs[(d4 + 1) * TILE + cb] = b.y;
        Bs[(d4 + 2) * TILE + cb] = b.z;
        Bs[(d4 + 3) * TILE + cb] = b.w;
    }
    __syncthreads();

    const int tx = t & 15;
    const int ty = t >> 4;
    float acc[8][8] = {};

#pragma unroll 8
    for (int k = 0; k < D; ++k) {
        int gk  = (k >> 2) & 7;
        int ab  = k * TILE + ((ty ^ gk) << 3);
        int bb0 = k * TILE + ((4 * tx) ^ (gk << 3));
        float4 a0 = *(const float4*)&As[ab];
        float4 a1 = *(const float4*)&As[ab + 4];
        float4 b0 = *(const float4*)&Bs[bb0];
        float4 b1 = *(const float4*)&Bs[bb0 + 64];
        float av[8] = {a0.x, a0.y, a0.z, a0.w, a1.x, a1.y, a1.z, a1.w};
        float bv[8] = {b0.x, b0.y, b0.z, b0.w, b1.x, b1.y, b1.z, b1.w};
#pragma unroll
        for (int i = 0; i < 8; ++i)
#pragma unroll
            for (int j = 0; j < 8; ++j)
                acc[i][j] += av[i] * bv[j];
    }

    float na[8], nb[8];
#pragma unroll
    for (int i = 0; i < 8; ++i) na[i] = nrm[row0 + 8 * ty + i];
#pragma unroll
    for (int q = 0; q < 4; ++q) {
        nb[q]     = nrm[N + col0 + 4 * tx + q];
        nb[4 + q] = nrm[N + col0 + 64 + 4 * tx + q];
    }

    float rmax[8];
#pragma unroll
    for (int i = 0; i < 8; ++i) rmax[i] = -FLT_MAX;

#pragma unroll
    for (int i = 0; i < 8; ++i) {
        float* po = out + (size_t)(row0 + 8 * ty + i) * N + col0 + 4 * tx;
        float4 o0, o1;
        float* f0 = (float*)&o0;
        float* f1 = (float*)&o1;
#pragma unroll
        for (int q = 0; q < 4; ++q) {
            float s0 = na[i] + nb[q] - 2.0f * acc[i][q];
            f0[q] = -fmaxf(s0, 0.0f);
            float s1 = na[i] + nb[4 + q] - 2.0f * acc[i][4 + q];
            f1[q] = -fmaxf(s1, 0.0f);
            rmax[i] = fmaxf(rmax[i], fmaxf(f0[q], f1[q]));
        }
        *(float4*)po        = o0;
        *(float4*)(po + 64) = o1;
    }

    if (have_tmax) {
#pragma unroll
        for (int i = 0; i < 8; ++i) {
            float mv = rmax[i];
            mv = fmaxf(mv, __shfl_down(mv, 8, 16));
            mv = fmaxf(mv, __shfl_down(mv, 4, 16));
            mv = fmaxf(mv, __shfl_down(mv, 2, 16));
            mv = fmaxf(mv, __shfl_down(mv, 1, 16));
            if (tx == 0)
                tmax[(size_t)(row0 + 8 * ty + i) * 64 + blockIdx.x] = mv;
        }
    }
}

__global__ __launch_bounds__(256) void topk_kernel(
    float* __restrict__ out, float* __restrict__ score_out,
    const float* __restrict__ tmax, int have_tmax)
{
    __shared__ unsigned long long cand[4][CAP];   // 32 KB
    __shared__ int scnt[4];

    const int t    = threadIdx.x;
    const int w    = t >> 6;
    const int lane = t & 63;
    const int r    = blockIdx.x * 4 + w;
    float* row = out + (size_t)r * N;
    const float4* row4 = (const float4*)row;

    float thr;
    float lm = -FLT_MAX;
    if (have_tmax) {
        float tm = tmax[(size_t)r * 64 + lane];
        unsigned km = ford(tm);
        int rk = 0;
#pragma unroll
        for (int l = 0; l < 64; ++l) {
            unsigned o = __shfl(km, l);
            rk += (o > km || (o == km && l < lane)) ? 1 : 0;
        }
        unsigned long long bm = __ballot(rk == 31);
        thr = __shfl(tm, __ffsll(bm) - 1);
    } else {
#pragma unroll 8
        for (int c = 0; c < 32; ++c) {
            float4 x = row4[c * 64 + lane];
            lm = fmaxf(lm, fmaxf(fmaxf(x.x, x.y), fmaxf(x.z, x.w)));
        }
        thr = lm;
        for (int off = 32; off > 0; off >>= 1)
            thr = fminf(thr, __shfl_xor(thr, off));
    }

    for (int attempt = 0; ; ++attempt) {
        if (lane == 0) scnt[w] = 0;
        __builtin_amdgcn_s_waitcnt(0xC07F);
        for (int c = 0; c < 32; ++c) {
            float4 x = row4[c * 64 + lane];
            float vs[4] = {x.x, x.y, x.z, x.w};
#pragma unroll
            for (int q = 0; q < 4; ++q) {
                float v = vs[q];
                lm = fmaxf(lm, v);
                if (v >= thr) {
                    int p = atomicAdd(&scnt[w], 1);
                    if (p < CAP) {
                        unsigned long long key =
                            ((unsigned long long)ford(v) << 32) |
                            (unsigned)(8191 - (4 * (c * 64 + lane) + q));
                        cand[w][p] = key;
                    }
                }
            }
        }
        __builtin_amdgcn_s_waitcnt(0xC07F);
        if (scnt[w] <= CAP || attempt == 1) break;
        unsigned kml = ford(lm);
        int rk2 = 0;
#pragma unroll
        for (int l = 0; l < 64; ++l) {
            unsigned o = __shfl(kml, l);
            rk2 += (o < kml || (o == kml && l < lane)) ? 1 : 0;
        }
        unsigned long long bm2 = __ballot(rk2 == 15);
        float t2 = __shfl(lm, __ffsll(bm2) - 1);
        thr = fmaxf(thr, t2);
    }
    const int n = min(scnt[w], CAP);

    unsigned long long mykey = 0ull;
    for (int it = 0; it < TOPK; ++it) {
        unsigned long long b = 0ull; int bp = 0;
        for (int q = lane; q < n; q += 64) {
            unsigned long long kk = cand[w][q];
            if (kk > b) { b = kk; bp = q; }
        }
        for (int off = 32; off > 0; off >>= 1) {
            unsigned long long ob = __shfl_down(b, off);
            int op = __shfl_down(bp, off);
            if (ob > b) { b = ob; bp = op; }
        }
        unsigned long long b0 = __shfl(b, 0);
        int bp0 = __shfl(bp, 0);
        if (lane == it) { mykey = b0; cand[w][bp0] = 0ull; }
    }

    float myv = 0.f; int myj = 0;
    if (lane < TOPK) {
        float sv = finv((unsigned)(mykey >> 32));
        myv = -sqrtf(-sv);
        myj = 8191 - (int)(mykey & 0xFFFFFFFFu);
    }
    float Mx = __shfl(myv, 0);
    float e = (lane < TOPK) ? expf(myv - Mx) : 0.f;
    float Z = e;
    for (int off = 32; off > 0; off >>= 1) Z += __shfl_xor(Z, off);
    float s = e / Z;
    if (lane < TOPK) score_out[(size_t)r * TOPK + lane] = s;

    const float4 zz = make_float4(0.f, 0.f, 0.f, 0.f);
#pragma unroll 8
    for (int c = 0; c < 32; ++c) ((float4*)row)[c * 64 + lane] = zz;
    __builtin_amdgcn_s_waitcnt(0x0F70);   // vmcnt(0)
    if (lane < TOPK) row[myj] = s;
}

// ---------------------------------------------------------------------------
extern "C" void kernel_launch(void* const* d_in, const int* in_sizes, int n_in,
                              void* d_out, int out_size, void* d_ws, size_t ws_size,
                              hipStream_t stream)
{
    const float* X1 = (const float*)d_in[0];
    const float* X2 = (const float*)d_in[1];
    float* out = (float*)d_out;
    float* score = out + (size_t)N * N;

    // sampled-path workspace layout:
    //   nrm : 2N floats    (64 KB)
    //   thr : N floats     (32 KB)
    //   cnt : N ints       (32 KB)
    //   Sm  : N*MS floats  (32 MB)
    //   cand: N*CAPC u64   (64 MB)
    float* nrm  = (float*)d_ws;
    float* thrv = nrm + 2 * N;
    int*   cnt  = (int*)(thrv + N);
    float* Sm   = (float*)(cnt + N);
    unsigned long long* cand = (unsigned long long*)(Sm + (size_t)N * MS);

    size_t need_new = (size_t)(4 * N) * sizeof(float)
                    + (size_t)N * MS * sizeof(float)
                    + (size_t)N * CAPC * sizeof(unsigned long long);

    // fallback layout: nrm, tmax
    float* tmax = nrm + 2 * N;
    size_t need_old = (size_t)(2 * N + (size_t)N * 64) * sizeof(float);

    norms_kernel<<<(2 * N + 255) / 256, 256, 0, stream>>>(X1, X2, nrm);

    if (ws_size >= need_new) {
        dim3 sgrid(MS / TILE, N / TILE);               // 8 x 64
        samp_gemm_kernel<<<sgrid, 256, 0, stream>>>(X1, X2, nrm, Sm);
        samp_thr_kernel<<<N / 4, 256, 0, stream>>>(Sm, thrv, cnt);
        dim3 grid(N / TILE, N / TILE);                 // 64 x 64
        cand_zero_kernel<<<grid, 256, 0, stream>>>(X1, X2, nrm, thrv, out, cand, cnt);
        topk_scatter_kernel<<<N / 4, 256, 0, stream>>>(out, score, cand, cnt);
    } else {
        int have_tmax = (ws_size >= need_old) ? 1 : 0;
        dim3 grid(N / TILE, N / TILE);
        dist_kernel<<<grid, 256, 0, stream>>>(X1, X2, nrm, out, tmax, have_tmax);
        topk_kernel<<<N / 4, 256, 0, stream>>>(out, score, tmax, have_tmax);
    }
}

// Round 3
// 521.330 us; speedup vs baseline: 1.9669x; 1.9669x over previous
//
#include <hip/hip_runtime.h>
#include <math.h>
#include <float.h>
#include <limits.h>

#define N 8192
#define D 64
#define TOPK 32
#define TILE 128
#define CAP 1024      // fallback path: per-wave LDS candidate cap
#define SLOT 32       // per-(row,stripe) candidate slots (u16 cols)
#define CAPR 512      // pass-3 per-row candidate list cap
#define MARGIN 0.3f   // 2*eps bound for bf16x3 approx error on sq-distance

typedef __attribute__((ext_vector_type(8))) short bf16x8;
typedef __attribute__((ext_vector_type(4))) float f32x4;

// orderable-uint encoding of float: a > b  <=>  ford(a) > ford(b)
__device__ __forceinline__ unsigned ford(float f) {
    unsigned u = __float_as_uint(f);
    return u ^ ((u & 0x80000000u) ? 0xFFFFFFFFu : 0x80000000u);
}
__device__ __forceinline__ float finv(unsigned u) {
    unsigned b = (u & 0x80000000u) ? (u ^ 0x80000000u) : ~u;
    return __uint_as_float(b);
}
// float -> bf16 bits (RNE); input data has no NaN/Inf
__device__ __forceinline__ unsigned short f2bf(float f) {
    unsigned u = __float_as_uint(f);
    unsigned r = u + 0x7FFFu + ((u >> 16) & 1u);
    return (unsigned short)(r >> 16);
}
__device__ __forceinline__ float bf2f(unsigned short h) {
    return __uint_as_float(((unsigned)h) << 16);
}

// ---------------------------------------------------------------------------
// Kernel 1: row norms (exact fp32) + bf16 hi/lo split of X1, X2.
// hi = bf16(x), lo = bf16(x - float(hi));  x ≈ hi + lo to ~2^-16 rel.
// ---------------------------------------------------------------------------
__global__ __launch_bounds__(256) void prep_kernel(
    const float* __restrict__ X1, const float* __restrict__ X2,
    float* __restrict__ nrm,
    unsigned short* __restrict__ X1h, unsigned short* __restrict__ X1l,
    unsigned short* __restrict__ X2h, unsigned short* __restrict__ X2l)
{
    int id = blockIdx.x * blockDim.x + threadIdx.x;
    if (id >= 2 * N) return;
    const float* X = (id < N) ? X1 : X2;
    unsigned short* H = (id < N) ? X1h : X2h;
    unsigned short* L = (id < N) ? X1l : X2l;
    int r = (id < N) ? id : id - N;
    const float4* p = (const float4*)(X + (size_t)r * D);
    ushort4* ph = (ushort4*)(H + (size_t)r * D);
    ushort4* pl = (ushort4*)(L + (size_t)r * D);
    float s = 0.f;
#pragma unroll
    for (int q = 0; q < D / 4; ++q) {
        float4 v = p[q];
        s += v.x * v.x + v.y * v.y + v.z * v.z + v.w * v.w;
        ushort4 h, l;
        h.x = f2bf(v.x); l.x = f2bf(v.x - bf2f(h.x));
        h.y = f2bf(v.y); l.y = f2bf(v.y - bf2f(h.y));
        h.z = f2bf(v.z); l.z = f2bf(v.z - bf2f(h.z));
        h.w = f2bf(v.w); l.w = f2bf(v.w - bf2f(h.w));
        ph[q] = h; pl[q] = l;
    }
    nrm[id] = s;
}

// ---------------------------------------------------------------------------
// Shared MFMA core: wave computes a 64x64 quadrant of the 128x128 block tile
// via 16x16x32 bf16 MFMA, 3-split (hh + hl + lh) over K=64 (2 k-steps).
// A frag: lane holds X1?[rW + mt*16 + (lane&15)][ks*32 + (lane>>4)*8 .. +8]
// B frag: lane holds X2?[cW + nt*16 + (lane&15)][ks*32 + (lane>>4)*8 .. +8]
// D frag: value reg of lane = C[row=(lane>>4)*4+reg][col=lane&15] (verified map)
// ---------------------------------------------------------------------------
#define MFMA16(a, b, c) __builtin_amdgcn_mfma_f32_16x16x32_bf16((a), (b), (c), 0, 0, 0)

__device__ __forceinline__ void mfma_core(
    const unsigned short* __restrict__ X1h, const unsigned short* __restrict__ X1l,
    const unsigned short* __restrict__ X2h, const unsigned short* __restrict__ X2l,
    int rW, int cW, int lane, f32x4 acc[4][4])
{
    const int l15 = lane & 15;
    const int lg8 = (lane >> 4) * 8;

    bf16x8 ah[4][2], al[4][2];
#pragma unroll
    for (int mt = 0; mt < 4; ++mt) {
        size_t ro = (size_t)(rW + mt * 16 + l15) * D + lg8;
        ah[mt][0] = *(const bf16x8*)(X1h + ro);
        ah[mt][1] = *(const bf16x8*)(X1h + ro + 32);
        al[mt][0] = *(const bf16x8*)(X1l + ro);
        al[mt][1] = *(const bf16x8*)(X1l + ro + 32);
    }
#pragma unroll
    for (int nt = 0; nt < 4; ++nt) {
        size_t co = (size_t)(cW + nt * 16 + l15) * D + lg8;
        bf16x8 bh0 = *(const bf16x8*)(X2h + co);
        bf16x8 bh1 = *(const bf16x8*)(X2h + co + 32);
        bf16x8 bl0 = *(const bf16x8*)(X2l + co);
        bf16x8 bl1 = *(const bf16x8*)(X2l + co + 32);
#pragma unroll
        for (int mt = 0; mt < 4; ++mt) {
            acc[mt][nt] = MFMA16(ah[mt][0], bh0, acc[mt][nt]);
            acc[mt][nt] = MFMA16(ah[mt][1], bh1, acc[mt][nt]);
            acc[mt][nt] = MFMA16(ah[mt][0], bl0, acc[mt][nt]);
            acc[mt][nt] = MFMA16(ah[mt][1], bl1, acc[mt][nt]);
            acc[mt][nt] = MFMA16(al[mt][0], bh0, acc[mt][nt]);
            acc[mt][nt] = MFMA16(al[mt][1], bh1, acc[mt][nt]);
        }
    }
}

// ---------------------------------------------------------------------------
// Kernel 2: MFMA GEMM pass 1 — per-(row, 128-col stripe) max of
// v_approx = -max(na + nb - 2*dot, 0)  -> tmax[row][stripe]  (2 MB)
// ---------------------------------------------------------------------------
__global__ __launch_bounds__(256) void mfma_tmax_kernel(
    const unsigned short* __restrict__ X1h, const unsigned short* __restrict__ X1l,
    const unsigned short* __restrict__ X2h, const unsigned short* __restrict__ X2l,
    const float* __restrict__ nrm, float* __restrict__ tmax)
{
    __shared__ float red[128][2];
    const int t = threadIdx.x;
    const int lane = t & 63, w = t >> 6;
    const int wr = w >> 1, wc = w & 1;
    const int row0 = blockIdx.y * TILE, col0 = blockIdx.x * TILE;
    const int rW = row0 + wr * 64, cW = col0 + wc * 64;
    const int l15 = lane & 15, lg = lane >> 4;

    f32x4 acc[4][4];
#pragma unroll
    for (int mt = 0; mt < 4; ++mt)
#pragma unroll
        for (int nt = 0; nt < 4; ++nt)
            acc[mt][nt] = (f32x4){0.f, 0.f, 0.f, 0.f};

    mfma_core(X1h, X1l, X2h, X2l, rW, cW, lane, acc);

    float nb[4];
#pragma unroll
    for (int nt = 0; nt < 4; ++nt) nb[nt] = nrm[N + cW + nt * 16 + l15];

    float rmax[4][4];
#pragma unroll
    for (int mt = 0; mt < 4; ++mt) {
#pragma unroll
        for (int reg = 0; reg < 4; ++reg) {
            float na = nrm[rW + mt * 16 + lg * 4 + reg];
            float m = -FLT_MAX;
#pragma unroll
            for (int nt = 0; nt < 4; ++nt) {
                float v = -fmaxf(na + nb[nt] - 2.0f * acc[mt][nt][reg], 0.f);
                m = fmaxf(m, v);
            }
            rmax[mt][reg] = m;
        }
    }
    // reduce across the 16 col-lanes of each lane group (xor stays in-group)
#pragma unroll
    for (int off = 1; off < 16; off <<= 1)
#pragma unroll
        for (int mt = 0; mt < 4; ++mt)
#pragma unroll
            for (int reg = 0; reg < 4; ++reg)
                rmax[mt][reg] = fmaxf(rmax[mt][reg], __shfl_xor(rmax[mt][reg], off));

    if (l15 == 0) {
#pragma unroll
        for (int mt = 0; mt < 4; ++mt)
#pragma unroll
            for (int reg = 0; reg < 4; ++reg)
                red[wr * 64 + mt * 16 + lg * 4 + reg][wc] = rmax[mt][reg];
    }
    __syncthreads();
    if (t < 128)
        tmax[(size_t)(row0 + t) * 64 + blockIdx.x] = fmaxf(red[t][0], red[t][1]);
}

// ---------------------------------------------------------------------------
// Kernel 3: thr[row] = 32nd-largest stripe max - MARGIN (sound lower bound
// on the exact 32nd value minus approx error; proof in header comment).
// ---------------------------------------------------------------------------
__global__ __launch_bounds__(256) void thr_kernel(
    const float* __restrict__ tmax, float* __restrict__ thr)
{
    const int t = threadIdx.x;
    const int w = t >> 6;
    const int lane = t & 63;
    const int r = blockIdx.x * 4 + w;

    float tm = tmax[(size_t)r * 64 + lane];
    unsigned km = ford(tm);
    int rk = 0;
#pragma unroll
    for (int l = 0; l < 64; ++l) {
        unsigned o = __shfl(km, l);
        rk += (o > km || (o == km && l < lane)) ? 1 : 0;
    }
    unsigned long long bm = __ballot(rk == 31);
    float tv = __shfl(tm, __ffsll(bm) - 1);
    if (lane == 0) thr[r] = tv - MARGIN;
}

// ---------------------------------------------------------------------------
// Kernel 4: MFMA GEMM pass 2 — zero-fill the out tile (268 MB total),
// append survivors (v_approx >= thr[row]) to deterministic per-(row,stripe)
// slots. LDS atomics only; NO global atomics (r2's killer).
// ---------------------------------------------------------------------------
__global__ __launch_bounds__(256) void mfma_cand_kernel(
    const unsigned short* __restrict__ X1h, const unsigned short* __restrict__ X1l,
    const unsigned short* __restrict__ X2h, const unsigned short* __restrict__ X2l,
    const float* __restrict__ nrm, const float* __restrict__ thr,
    float* __restrict__ out, unsigned short* __restrict__ cand,
    int* __restrict__ cnt)
{
    __shared__ unsigned short lbuf[128][SLOT];   // 8 KB
    __shared__ int lcnt[128];

    const int t = threadIdx.x;
    const int lane = t & 63, w = t >> 6;
    const int wr = w >> 1, wc = w & 1;
    const int row0 = blockIdx.y * TILE, col0 = blockIdx.x * TILE;
    const int rW = row0 + wr * 64, cW = col0 + wc * 64;
    const int l15 = lane & 15, lg = lane >> 4;

    if (t < 128) lcnt[t] = 0;
    __syncthreads();

    f32x4 acc[4][4];
#pragma unroll
    for (int mt = 0; mt < 4; ++mt)
#pragma unroll
        for (int nt = 0; nt < 4; ++nt)
            acc[mt][nt] = (f32x4){0.f, 0.f, 0.f, 0.f};

    mfma_core(X1h, X1l, X2h, X2l, rW, cW, lane, acc);

    // zero-fill this block's 128x128 out tile, coalesced float4 stores
    const float4 zz = make_float4(0.f, 0.f, 0.f, 0.f);
#pragma unroll
    for (int p = 0; p < 16; ++p) {
        int lin = p * 256 + t;
        int rr = lin >> 5;            // 0..127
        int c4 = (lin & 31) << 2;     // 0..124
        *(float4*)(out + (size_t)(row0 + rr) * N + col0 + c4) = zz;
    }

    float nb[4];
#pragma unroll
    for (int nt = 0; nt < 4; ++nt) nb[nt] = nrm[N + cW + nt * 16 + l15];

#pragma unroll
    for (int mt = 0; mt < 4; ++mt) {
#pragma unroll
        for (int reg = 0; reg < 4; ++reg) {
            int lrow = wr * 64 + mt * 16 + lg * 4 + reg;   // 0..127
            float na = nrm[row0 + lrow];
            float th = thr[row0 + lrow];
#pragma unroll
            for (int nt = 0; nt < 4; ++nt) {
                float v = -fmaxf(na + nb[nt] - 2.0f * acc[mt][nt][reg], 0.f);
                if (v >= th) {
                    int p0 = atomicAdd(&lcnt[lrow], 1);
                    if (p0 < SLOT)
                        lbuf[lrow][p0] = (unsigned short)(wc * 64 + nt * 16 + l15);
                }
            }
        }
    }
    __syncthreads();

    if (t < 128) {
        int c = lcnt[t];
        size_t sidx = (size_t)(row0 + t) * 64 + blockIdx.x;
        cnt[sidx] = c;                        // raw count (overflow detectable)
        unsigned short* cg = cand + sidx * SLOT;
        int m = min(c, SLOT);
        for (int j = 0; j < m; ++j) cg[j] = lbuf[t][j];
    }
}

// ---------------------------------------------------------------------------
// Kernel 5: one wave per row. Gather candidate cols (prefix-sum placement,
// overflow stripe -> all 128 cols: sound), recompute EXACT fp32 distances,
// exact top-32 (same key/tie-break as proven path), sqrt+softmax, scatter.
// ---------------------------------------------------------------------------
__global__ __launch_bounds__(256) void exact_topk_kernel(
    const float* __restrict__ X1, const float* __restrict__ X2,
    const float* __restrict__ nrm,
    const unsigned short* __restrict__ cand, const int* __restrict__ cnt,
    float* __restrict__ out, float* __restrict__ score_out)
{
    __shared__ float x1r[4][D];                     // 4 x 256 B
    __shared__ unsigned short lst[4][CAPR];         // 4 x 1 KB
    __shared__ unsigned long long kl[4][CAPR];      // 4 x 4 KB

    const int t = threadIdx.x;
    const int w = t >> 6;
    const int lane = t & 63;
    const int r = blockIdx.x * 4 + w;

    x1r[w][lane] = X1[(size_t)r * D + lane];

    int c = cnt[(size_t)r * 64 + lane];
    int eff = (c > SLOT) ? 128 : c;        // overflow: take whole stripe
    int pre = eff;
#pragma unroll
    for (int o = 1; o < 64; o <<= 1) {
        int pv = __shfl_up(pre, o);
        if (lane >= o) pre += pv;
    }
    int off0 = pre - eff;
    int M = __shfl(pre, 63);
    if (M > CAPR) M = CAPR;

    const unsigned short* cg = cand + ((size_t)r * 64 + lane) * SLOT;
    for (int j = 0; j < eff; ++j) {
        int pos = off0 + j;
        if (pos < CAPR) {
            int colloc = (c > SLOT) ? j : (int)cg[j];
            lst[w][pos] = (unsigned short)(lane * 128 + colloc);
        }
    }
    __builtin_amdgcn_s_waitcnt(0xC07F);   // lgkmcnt(0): lst + x1r visible in-wave

    float na = nrm[r];
    for (int q = lane; q < M; q += 64) {
        int col = lst[w][q];
        const float4* xr = (const float4*)(X2 + (size_t)col * D);
        float dot = 0.f;
#pragma unroll
        for (int i = 0; i < D / 4; ++i) {
            float4 xv = xr[i];
            dot += x1r[w][4 * i + 0] * xv.x + x1r[w][4 * i + 1] * xv.y
                 + x1r[w][4 * i + 2] * xv.z + x1r[w][4 * i + 3] * xv.w;
        }
        float v = -fmaxf(na + nrm[N + col] - 2.0f * dot, 0.f);
        kl[w][q] = ((unsigned long long)ford(v) << 32) | (unsigned)(8191 - col);
    }
    __builtin_amdgcn_s_waitcnt(0xC07F);

    unsigned long long mykey = 0ull;
    for (int it = 0; it < TOPK; ++it) {
        unsigned long long b = 0ull; int bp = 0;
        for (int q = lane; q < M; q += 64) {
            unsigned long long kk = kl[w][q];
            if (kk > b) { b = kk; bp = q; }
        }
        for (int off = 32; off > 0; off >>= 1) {
            unsigned long long ob = __shfl_down(b, off);
            int op = __shfl_down(bp, off);
            if (ob > b) { b = ob; bp = op; }
        }
        unsigned long long b0 = __shfl(b, 0);
        int bp0 = __shfl(bp, 0);
        if (lane == it) { mykey = b0; kl[w][bp0] = 0ull; }
    }

    float myv = -FLT_MAX; int myj = 0;
    if (lane < TOPK && mykey != 0ull) {
        float sv = finv((unsigned)(mykey >> 32));   // exact -max(sq,0)
        myv = -sqrtf(-sv);
        myj = 8191 - (int)(mykey & 0xFFFFFFFFu);
    }
    float Mx = __shfl(myv, 0);
    float e = (lane < TOPK && mykey != 0ull) ? expf(myv - Mx) : 0.f;
    float Z = e;
    for (int off = 32; off > 0; off >>= 1) Z += __shfl_xor(Z, off);
    float s = e / Z;
    if (lane < TOPK && mykey != 0ull) {
        score_out[(size_t)r * TOPK + lane] = s;
        out[(size_t)r * N + myj] = s;    // zeros laid down by pass 2
    }
}

// ---------------------------------------------------------------------------
// FALLBACK path (workspace too small): r0 verified pipeline.
// ---------------------------------------------------------------------------
__global__ __launch_bounds__(256) void norms_kernel(
    const float* __restrict__ X1, const float* __restrict__ X2,
    float* __restrict__ nrm)
{
    int id = blockIdx.x * blockDim.x + threadIdx.x;
    if (id >= 2 * N) return;
    const float* X = (id < N) ? X1 : X2;
    int r = (id < N) ? id : id - N;
    const float4* p = (const float4*)(X + (size_t)r * D);
    float s = 0.f;
#pragma unroll
    for (int q = 0; q < D / 4; ++q) {
        float4 v = p[q];
        s += v.x * v.x + v.y * v.y + v.z * v.z + v.w * v.w;
    }
    nrm[id] = s;
}

__global__ __launch_bounds__(256, 2) void dist_kernel(
    const float* __restrict__ X1, const float* __restrict__ X2,
    const float* __restrict__ nrm, float* __restrict__ out,
    float* __restrict__ tmax, int have_tmax)
{
    __shared__ float As[D * TILE];
    __shared__ float Bs[D * TILE];

    const int t = threadIdx.x;
    const int row0 = blockIdx.y * TILE;
    const int col0 = blockIdx.x * TILE;

#pragma unroll
    for (int p = 0; p < 8; ++p) {
        int lin = p * 256 + t;
        int r   = lin >> 4;
        int d4  = (lin & 15) << 2;
        int g   = (d4 >> 2) & 7;
        int cb  = r ^ (g << 3);
        float4 a = *(const float4*)(X1 + (size_t)(row0 + r) * D + d4);
        As[(d4 + 0) * TILE + cb] = a.x;
        As[(d4 + 1) * TILE + cb] = a.y;
        As[(d4 + 2) * TILE + cb] = a.z;
        As[(d4 + 3) * TILE + cb] = a.w;
        float4 b = *(const float4*)(X2 + (size_t)(col0 + r) * D + d4);
        Bs[(d4 + 0) * TILE + cb] = b.x;
        Bs[(d4 + 1) * TILE + cb] = b.y;
        Bs[(d4 + 2) * TILE + cb] = b.z;
        Bs[(d4 + 3) * TILE + cb] = b.w;
    }
    __syncthreads();

    const int tx = t & 15;
    const int ty = t >> 4;
    float acc[8][8] = {};

#pragma unroll 8
    for (int k = 0; k < D; ++k) {
        int gk  = (k >> 2) & 7;
        int ab  = k * TILE + ((ty ^ gk) << 3);
        int bb0 = k * TILE + ((4 * tx) ^ (gk << 3));
        float4 a0 = *(const float4*)&As[ab];
        float4 a1 = *(const float4*)&As[ab + 4];
        float4 b0 = *(const float4*)&Bs[bb0];
        float4 b1 = *(const float4*)&Bs[bb0 + 64];
        float av[8] = {a0.x, a0.y, a0.z, a0.w, a1.x, a1.y, a1.z, a1.w};
        float bv[8] = {b0.x, b0.y, b0.z, b0.w, b1.x, b1.y, b1.z, b1.w};
#pragma unroll
        for (int i = 0; i < 8; ++i)
#pragma unroll
            for (int j = 0; j < 8; ++j)
                acc[i][j] += av[i] * bv[j];
    }

    float na[8], nb[8];
#pragma unroll
    for (int i = 0; i < 8; ++i) na[i] = nrm[row0 + 8 * ty + i];
#pragma unroll
    for (int q = 0; q < 4; ++q) {
        nb[q]     = nrm[N + col0 + 4 * tx + q];
        nb[4 + q] = nrm[N + col0 + 64 + 4 * tx + q];
    }

    float rmax[8];
#pragma unroll
    for (int i = 0; i < 8; ++i) rmax[i] = -FLT_MAX;

#pragma unroll
    for (int i = 0; i < 8; ++i) {
        float* po = out + (size_t)(row0 + 8 * ty + i) * N + col0 + 4 * tx;
        float4 o0, o1;
        float* f0 = (float*)&o0;
        float* f1 = (float*)&o1;
#pragma unroll
        for (int q = 0; q < 4; ++q) {
            float s0 = na[i] + nb[q] - 2.0f * acc[i][q];
            f0[q] = -fmaxf(s0, 0.0f);
            float s1 = na[i] + nb[4 + q] - 2.0f * acc[i][4 + q];
            f1[q] = -fmaxf(s1, 0.0f);
            rmax[i] = fmaxf(rmax[i], fmaxf(f0[q], f1[q]));
        }
        *(float4*)po        = o0;
        *(float4*)(po + 64) = o1;
    }

    if (have_tmax) {
#pragma unroll
        for (int i = 0; i < 8; ++i) {
            float mv = rmax[i];
            mv = fmaxf(mv, __shfl_down(mv, 8, 16));
            mv = fmaxf(mv, __shfl_down(mv, 4, 16));
            mv = fmaxf(mv, __shfl_down(mv, 2, 16));
            mv = fmaxf(mv, __shfl_down(mv, 1, 16));
            if (tx == 0)
                tmax[(size_t)(row0 + 8 * ty + i) * 64 + blockIdx.x] = mv;
        }
    }
}

__global__ __launch_bounds__(256) void topk_kernel(
    float* __restrict__ out, float* __restrict__ score_out,
    const float* __restrict__ tmax, int have_tmax)
{
    __shared__ unsigned long long candl[4][CAP];   // 32 KB
    __shared__ int scnt[4];

    const int t    = threadIdx.x;
    const int w    = t >> 6;
    const int lane = t & 63;
    const int r    = blockIdx.x * 4 + w;
    float* row = out + (size_t)r * N;
    const float4* row4 = (const float4*)row;

    float thr;
    float lm = -FLT_MAX;
    if (have_tmax) {
        float tm = tmax[(size_t)r * 64 + lane];
        unsigned km = ford(tm);
        int rk = 0;
#pragma unroll
        for (int l = 0; l < 64; ++l) {
            unsigned o = __shfl(km, l);
            rk += (o > km || (o == km && l < lane)) ? 1 : 0;
        }
        unsigned long long bm = __ballot(rk == 31);
        thr = __shfl(tm, __ffsll(bm) - 1);
    } else {
#pragma unroll 8
        for (int c = 0; c < 32; ++c) {
            float4 x = row4[c * 64 + lane];
            lm = fmaxf(lm, fmaxf(fmaxf(x.x, x.y), fmaxf(x.z, x.w)));
        }
        thr = lm;
        for (int off = 32; off > 0; off >>= 1)
            thr = fminf(thr, __shfl_xor(thr, off));
    }

    for (int attempt = 0; ; ++attempt) {
        if (lane == 0) scnt[w] = 0;
        __builtin_amdgcn_s_waitcnt(0xC07F);
        for (int c = 0; c < 32; ++c) {
            float4 x = row4[c * 64 + lane];
            float vs[4] = {x.x, x.y, x.z, x.w};
#pragma unroll
            for (int q = 0; q < 4; ++q) {
                float v = vs[q];
                lm = fmaxf(lm, v);
                if (v >= thr) {
                    int p = atomicAdd(&scnt[w], 1);
                    if (p < CAP) {
                        unsigned long long key =
                            ((unsigned long long)ford(v) << 32) |
                            (unsigned)(8191 - (4 * (c * 64 + lane) + q));
                        candl[w][p] = key;
                    }
                }
            }
        }
        __builtin_amdgcn_s_waitcnt(0xC07F);
        if (scnt[w] <= CAP || attempt == 1) break;
        unsigned kml = ford(lm);
        int rk2 = 0;
#pragma unroll
        for (int l = 0; l < 64; ++l) {
            unsigned o = __shfl(kml, l);
            rk2 += (o < kml || (o == kml && l < lane)) ? 1 : 0;
        }
        unsigned long long bm2 = __ballot(rk2 == 15);
        float t2 = __shfl(lm, __ffsll(bm2) - 1);
        thr = fmaxf(thr, t2);
    }
    const int n = min(scnt[w], CAP);

    unsigned long long mykey = 0ull;
    for (int it = 0; it < TOPK; ++it) {
        unsigned long long b = 0ull; int bp = 0;
        for (int q = lane; q < n; q += 64) {
            unsigned long long kk = candl[w][q];
            if (kk > b) { b = kk; bp = q; }
        }
        for (int off = 32; off > 0; off >>= 1) {
            unsigned long long ob = __shfl_down(b, off);
            int op = __shfl_down(bp, off);
            if (ob > b) { b = ob; bp = op; }
        }
        unsigned long long b0 = __shfl(b, 0);
        int bp0 = __shfl(bp, 0);
        if (lane == it) { mykey = b0; candl[w][bp0] = 0ull; }
    }

    float myv = 0.f; int myj = 0;
    if (lane < TOPK) {
        float sv = finv((unsigned)(mykey >> 32));
        myv = -sqrtf(-sv);
        myj = 8191 - (int)(mykey & 0xFFFFFFFFu);
    }
    float Mx = __shfl(myv, 0);
    float e = (lane < TOPK) ? expf(myv - Mx) : 0.f;
    float Z = e;
    for (int off = 32; off > 0; off >>= 1) Z += __shfl_xor(Z, off);
    float s = e / Z;
    if (lane < TOPK) score_out[(size_t)r * TOPK + lane] = s;

    const float4 zz = make_float4(0.f, 0.f, 0.f, 0.f);
#pragma unroll 8
    for (int c = 0; c < 32; ++c) ((float4*)row)[c * 64 + lane] = zz;
    __builtin_amdgcn_s_waitcnt(0x0F70);   // vmcnt(0)
    if (lane < TOPK) row[myj] = s;
}

// ---------------------------------------------------------------------------
extern "C" void kernel_launch(void* const* d_in, const int* in_sizes, int n_in,
                              void* d_out, int out_size, void* d_ws, size_t ws_size,
                              hipStream_t stream)
{
    const float* X1 = (const float*)d_in[0];
    const float* X2 = (const float*)d_in[1];
    float* out = (float*)d_out;
    float* score = out + (size_t)N * N;

    // MFMA-path workspace layout (all blocks 16B-aligned by construction):
    //   nrm  : 2N f32          (64 KB)
    //   tmax : N*64 f32        (2 MB)
    //   thr  : N f32           (32 KB)
    //   cnt  : N*64 i32        (2 MB)
    //   X1h/X1l/X2h/X2l : N*64 u16 each (1 MB each)
    //   cand : N*64*SLOT u16   (32 MB)
    char* base = (char*)d_ws;
    float* nrm  = (float*)base;
    float* tmax = nrm + 2 * N;
    float* thrv = tmax + (size_t)N * 64;
    int*   cnt  = (int*)(thrv + N);
    unsigned short* X1h = (unsigned short*)(cnt + (size_t)N * 64);
    unsigned short* X1l = X1h + (size_t)N * D;
    unsigned short* X2h = X1l + (size_t)N * D;
    unsigned short* X2l = X2h + (size_t)N * D;
    unsigned short* cand = X2l + (size_t)N * D;

    size_t need_new = (size_t)(2 * N + (size_t)N * 64 + N) * sizeof(float)
                    + (size_t)N * 64 * sizeof(int)
                    + 4 * (size_t)N * D * sizeof(unsigned short)
                    + (size_t)N * 64 * SLOT * sizeof(unsigned short);
    size_t need_old = (size_t)(2 * N + (size_t)N * 64) * sizeof(float);

    if (ws_size >= need_new) {
        prep_kernel<<<(2 * N + 255) / 256, 256, 0, stream>>>(
            X1, X2, nrm, X1h, X1l, X2h, X2l);
        dim3 grid(N / TILE, N / TILE);   // 64 x 64
        mfma_tmax_kernel<<<grid, 256, 0, stream>>>(X1h, X1l, X2h, X2l, nrm, tmax);
        thr_kernel<<<N / 4, 256, 0, stream>>>(tmax, thrv);
        mfma_cand_kernel<<<grid, 256, 0, stream>>>(
            X1h, X1l, X2h, X2l, nrm, thrv, out, cand, cnt);
        exact_topk_kernel<<<N / 4, 256, 0, stream>>>(
            X1, X2, nrm, cand, cnt, out, score);
    } else {
        float* tmax_f = nrm + 2 * N;
        int have_tmax = (ws_size >= need_old) ? 1 : 0;
        norms_kernel<<<(2 * N + 255) / 256, 256, 0, stream>>>(X1, X2, nrm);
        dim3 grid(N / TILE, N / TILE);
        dist_kernel<<<grid, 256, 0, stream>>>(X1, X2, nrm, out, tmax_f, have_tmax);
        topk_kernel<<<N / 4, 256, 0, stream>>>(out, score, tmax_f, have_tmax);
    }
}

// Round 4
// 468.125 us; speedup vs baseline: 2.1905x; 1.1137x over previous
//
#include <hip/hip_runtime.h>
#include <math.h>
#include <float.h>
#include <limits.h>

#define N 8192
#define D 64
#define TOPK 32
#define TILE 128
#define CAP 1024      // fallback path: per-wave LDS candidate cap
#define SLOT 32       // per-(row,stripe) candidate slots (u16 cols)
#define CAPR 768      // pass-3 per-row candidate list cap
#define MARGIN 0.75f  // sound double-dip bound for fp16 sq-distance error

typedef _Float16 f16x8 __attribute__((ext_vector_type(8)));
typedef _Float16 f16x4v __attribute__((ext_vector_type(4)));
typedef __attribute__((ext_vector_type(4))) float f32x4;

// orderable-uint encoding of float: a > b  <=>  ford(a) > ford(b)
__device__ __forceinline__ unsigned ford(float f) {
    unsigned u = __float_as_uint(f);
    return u ^ ((u & 0x80000000u) ? 0xFFFFFFFFu : 0x80000000u);
}
__device__ __forceinline__ float finv(unsigned u) {
    unsigned b = (u & 0x80000000u) ? (u ^ 0x80000000u) : ~u;
    return __uint_as_float(b);
}

// ---------------------------------------------------------------------------
// Kernel 1: row norms (exact fp32) + fp16 conversion of X1, X2 (RNE).
// ---------------------------------------------------------------------------
__global__ __launch_bounds__(256) void prep_kernel(
    const float* __restrict__ X1, const float* __restrict__ X2,
    float* __restrict__ nrm,
    _Float16* __restrict__ X1f, _Float16* __restrict__ X2f)
{
    int id = blockIdx.x * blockDim.x + threadIdx.x;
    if (id >= 2 * N) return;
    const float* X = (id < N) ? X1 : X2;
    _Float16* H = (id < N) ? X1f : X2f;
    int r = (id < N) ? id : id - N;
    const float4* p = (const float4*)(X + (size_t)r * D);
    f16x4v* ph = (f16x4v*)(H + (size_t)r * D);
    float s = 0.f;
#pragma unroll
    for (int q = 0; q < D / 4; ++q) {
        float4 v = p[q];
        s += v.x * v.x + v.y * v.y + v.z * v.z + v.w * v.w;
        f16x4v h;
        h[0] = (_Float16)v.x; h[1] = (_Float16)v.y;
        h[2] = (_Float16)v.z; h[3] = (_Float16)v.w;
        ph[q] = h;
    }
    nrm[id] = s;
}

// ---------------------------------------------------------------------------
// Shared MFMA core: wave computes a 64x64 quadrant of the 128x128 block tile
// via 16x16x32 fp16 MFMA over K=64 (2 k-halves). Single product (no split):
// fp16 error bounded by MARGIN; pass 3 recomputes exact fp32.
// A frag: lane holds X1f[rW + mt*16 + (lane&15)][kh*32 + (lane>>4)*8 .. +8]
// B frag: lane holds X2f[cW + nt*16 + (lane&15)][kh*32 + (lane>>4)*8 .. +8]
// D frag: reg of lane = C[row=(lane>>4)*4+reg][col=lane&15] (verified r3)
// ---------------------------------------------------------------------------
#define MFMA16F(a, b, c) __builtin_amdgcn_mfma_f32_16x16x32_f16((a), (b), (c), 0, 0, 0)

__device__ __forceinline__ void mfma_core(
    const _Float16* __restrict__ X1f, const _Float16* __restrict__ X2f,
    int rW, int cW, int lane, f32x4 acc[4][4])
{
    const int l15 = lane & 15;
    const int lg8 = (lane >> 4) * 8;

    f16x8 ah[4][2];
#pragma unroll
    for (int mt = 0; mt < 4; ++mt) {
        size_t ro = (size_t)(rW + mt * 16 + l15) * D + lg8;
        ah[mt][0] = *(const f16x8*)(X1f + ro);
        ah[mt][1] = *(const f16x8*)(X1f + ro + 32);
    }
#pragma unroll
    for (int nt = 0; nt < 4; ++nt) {
        size_t co = (size_t)(cW + nt * 16 + l15) * D + lg8;
        f16x8 b0 = *(const f16x8*)(X2f + co);
        f16x8 b1 = *(const f16x8*)(X2f + co + 32);
#pragma unroll
        for (int mt = 0; mt < 4; ++mt) {
            acc[mt][nt] = MFMA16F(ah[mt][0], b0, acc[mt][nt]);
            acc[mt][nt] = MFMA16F(ah[mt][1], b1, acc[mt][nt]);
        }
    }
}

// ---------------------------------------------------------------------------
// Kernel 2: fp16 MFMA GEMM pass 1 — per-(row, 128-col stripe) max of
// v_f16 = -max(na + nb - 2*dot, 0)  -> tmax[row][stripe]  (2 MB)
// ---------------------------------------------------------------------------
__global__ __launch_bounds__(256) void mfma_tmax_kernel(
    const _Float16* __restrict__ X1f, const _Float16* __restrict__ X2f,
    const float* __restrict__ nrm, float* __restrict__ tmax)
{
    __shared__ float red[128][2];
    const int t = threadIdx.x;
    const int lane = t & 63, w = t >> 6;
    const int wr = w >> 1, wc = w & 1;
    const int row0 = blockIdx.y * TILE, col0 = blockIdx.x * TILE;
    const int rW = row0 + wr * 64, cW = col0 + wc * 64;
    const int l15 = lane & 15, lg = lane >> 4;

    f32x4 acc[4][4];
#pragma unroll
    for (int mt = 0; mt < 4; ++mt)
#pragma unroll
        for (int nt = 0; nt < 4; ++nt)
            acc[mt][nt] = (f32x4){0.f, 0.f, 0.f, 0.f};

    mfma_core(X1f, X2f, rW, cW, lane, acc);

    float nb[4];
#pragma unroll
    for (int nt = 0; nt < 4; ++nt) nb[nt] = nrm[N + cW + nt * 16 + l15];

    float rmax[4][4];
#pragma unroll
    for (int mt = 0; mt < 4; ++mt) {
#pragma unroll
        for (int reg = 0; reg < 4; ++reg) {
            float na = nrm[rW + mt * 16 + lg * 4 + reg];
            float m = -FLT_MAX;
#pragma unroll
            for (int nt = 0; nt < 4; ++nt) {
                float v = -fmaxf(na + nb[nt] - 2.0f * acc[mt][nt][reg], 0.f);
                m = fmaxf(m, v);
            }
            rmax[mt][reg] = m;
        }
    }
    // reduce across the 16 col-lanes of each lane group (xor stays in-group)
#pragma unroll
    for (int off = 1; off < 16; off <<= 1)
#pragma unroll
        for (int mt = 0; mt < 4; ++mt)
#pragma unroll
            for (int reg = 0; reg < 4; ++reg)
                rmax[mt][reg] = fmaxf(rmax[mt][reg], __shfl_xor(rmax[mt][reg], off));

    if (l15 == 0) {
#pragma unroll
        for (int mt = 0; mt < 4; ++mt)
#pragma unroll
            for (int reg = 0; reg < 4; ++reg)
                red[wr * 64 + mt * 16 + lg * 4 + reg][wc] = rmax[mt][reg];
    }
    __syncthreads();
    if (t < 128)
        tmax[(size_t)(row0 + t) * 64 + blockIdx.x] = fmaxf(red[t][0], red[t][1]);
}

// ---------------------------------------------------------------------------
// Kernel 3: thr[row] = 32nd-largest stripe max - MARGIN.
// Sound: >=32 values have v_f16 >= T_A, so f16-rank32 >= T_A; any true
// top-32 x has v_exact(x) >= exact-rank32 >= f16-rank32 - e >= T_A - e,
// hence v_f16(x) >= T_A - 2e; MARGIN = 2e (worst-case fp16 bound).
// ---------------------------------------------------------------------------
__global__ __launch_bounds__(256) void thr_kernel(
    const float* __restrict__ tmax, float* __restrict__ thr)
{
    const int t = threadIdx.x;
    const int w = t >> 6;
    const int lane = t & 63;
    const int r = blockIdx.x * 4 + w;

    float tm = tmax[(size_t)r * 64 + lane];
    unsigned km = ford(tm);
    int rk = 0;
#pragma unroll
    for (int l = 0; l < 64; ++l) {
        unsigned o = __shfl(km, l);
        rk += (o > km || (o == km && l < lane)) ? 1 : 0;
    }
    unsigned long long bm = __ballot(rk == 31);
    float tv = __shfl(tm, __ffsll(bm) - 1);
    if (lane == 0) thr[r] = tv - MARGIN;
}

// ---------------------------------------------------------------------------
// Kernel 4: fp16 MFMA GEMM pass 2 — zero-fill the out tile (268 MB total),
// append survivors (v_f16 >= thr[row]) to deterministic per-(row,stripe)
// slots. LDS atomics only; NO global atomics.
// ---------------------------------------------------------------------------
__global__ __launch_bounds__(256) void mfma_cand_kernel(
    const _Float16* __restrict__ X1f, const _Float16* __restrict__ X2f,
    const float* __restrict__ nrm, const float* __restrict__ thr,
    float* __restrict__ out, unsigned short* __restrict__ cand,
    int* __restrict__ cnt)
{
    __shared__ unsigned short lbuf[128][SLOT];   // 8 KB
    __shared__ int lcnt[128];

    const int t = threadIdx.x;
    const int lane = t & 63, w = t >> 6;
    const int wr = w >> 1, wc = w & 1;
    const int row0 = blockIdx.y * TILE, col0 = blockIdx.x * TILE;
    const int rW = row0 + wr * 64, cW = col0 + wc * 64;
    const int l15 = lane & 15, lg = lane >> 4;

    if (t < 128) lcnt[t] = 0;
    __syncthreads();

    // zero-fill this block's 128x128 out tile first: stores are independent
    // of the MFMAs, so they drain under the compute.
    const float4 zz = make_float4(0.f, 0.f, 0.f, 0.f);
#pragma unroll
    for (int p = 0; p < 16; ++p) {
        int lin = p * 256 + t;
        int rr = lin >> 5;            // 0..127
        int c4 = (lin & 31) << 2;     // 0..124
        *(float4*)(out + (size_t)(row0 + rr) * N + col0 + c4) = zz;
    }

    f32x4 acc[4][4];
#pragma unroll
    for (int mt = 0; mt < 4; ++mt)
#pragma unroll
        for (int nt = 0; nt < 4; ++nt)
            acc[mt][nt] = (f32x4){0.f, 0.f, 0.f, 0.f};

    mfma_core(X1f, X2f, rW, cW, lane, acc);

    float nb[4];
#pragma unroll
    for (int nt = 0; nt < 4; ++nt) nb[nt] = nrm[N + cW + nt * 16 + l15];

#pragma unroll
    for (int mt = 0; mt < 4; ++mt) {
#pragma unroll
        for (int reg = 0; reg < 4; ++reg) {
            int lrow = wr * 64 + mt * 16 + lg * 4 + reg;   // 0..127
            float na = nrm[row0 + lrow];
            float th = thr[row0 + lrow];
#pragma unroll
            for (int nt = 0; nt < 4; ++nt) {
                float v = -fmaxf(na + nb[nt] - 2.0f * acc[mt][nt][reg], 0.f);
                if (v >= th) {
                    int p0 = atomicAdd(&lcnt[lrow], 1);
                    if (p0 < SLOT)
                        lbuf[lrow][p0] = (unsigned short)(wc * 64 + nt * 16 + l15);
                }
            }
        }
    }
    __syncthreads();

    if (t < 128) {
        int c = lcnt[t];
        size_t sidx = (size_t)(row0 + t) * 64 + blockIdx.x;
        cnt[sidx] = c;                        // raw count (overflow detectable)
        unsigned short* cg = cand + sidx * SLOT;
        int m = min(c, SLOT);
        for (int j = 0; j < m; ++j) cg[j] = lbuf[t][j];
    }
}

// ---------------------------------------------------------------------------
// Kernel 5: one wave per row. Gather candidate cols (prefix-sum placement,
// overflow stripe -> all 128 cols: sound), recompute EXACT fp32 distances,
// exact top-32 (same key/tie-break as proven path), sqrt+softmax, scatter.
// ---------------------------------------------------------------------------
__global__ __launch_bounds__(256) void exact_topk_kernel(
    const float* __restrict__ X1, const float* __restrict__ X2,
    const float* __restrict__ nrm,
    const unsigned short* __restrict__ cand, const int* __restrict__ cnt,
    float* __restrict__ out, float* __restrict__ score_out)
{
    __shared__ float x1r[4][D];                     // 4 x 256 B
    __shared__ unsigned short lst[4][CAPR];         // 4 x 1.5 KB
    __shared__ unsigned long long kl[4][CAPR];      // 4 x 6 KB

    const int t = threadIdx.x;
    const int w = t >> 6;
    const int lane = t & 63;
    const int r = blockIdx.x * 4 + w;

    x1r[w][lane] = X1[(size_t)r * D + lane];

    int c = cnt[(size_t)r * 64 + lane];
    int eff = (c > SLOT) ? 128 : c;        // overflow: take whole stripe
    int pre = eff;
#pragma unroll
    for (int o = 1; o < 64; o <<= 1) {
        int pv = __shfl_up(pre, o);
        if (lane >= o) pre += pv;
    }
    int off0 = pre - eff;
    int M = __shfl(pre, 63);
    if (M > CAPR) M = CAPR;

    const unsigned short* cg = cand + ((size_t)r * 64 + lane) * SLOT;
    for (int j = 0; j < eff; ++j) {
        int pos = off0 + j;
        if (pos < CAPR) {
            int colloc = (c > SLOT) ? j : (int)cg[j];
            lst[w][pos] = (unsigned short)(lane * 128 + colloc);
        }
    }
    __builtin_amdgcn_s_waitcnt(0xC07F);   // lgkmcnt(0): lst + x1r visible in-wave

    float na = nrm[r];
    for (int q = lane; q < M; q += 64) {
        int col = lst[w][q];
        const float4* xr = (const float4*)(X2 + (size_t)col * D);
        float dot = 0.f;
#pragma unroll
        for (int i = 0; i < D / 4; ++i) {
            float4 xv = xr[i];
            dot += x1r[w][4 * i + 0] * xv.x + x1r[w][4 * i + 1] * xv.y
                 + x1r[w][4 * i + 2] * xv.z + x1r[w][4 * i + 3] * xv.w;
        }
        float v = -fmaxf(na + nrm[N + col] - 2.0f * dot, 0.f);
        kl[w][q] = ((unsigned long long)ford(v) << 32) | (unsigned)(8191 - col);
    }
    __builtin_amdgcn_s_waitcnt(0xC07F);

    unsigned long long mykey = 0ull;
    for (int it = 0; it < TOPK; ++it) {
        unsigned long long b = 0ull; int bp = 0;
        for (int q = lane; q < M; q += 64) {
            unsigned long long kk = kl[w][q];
            if (kk > b) { b = kk; bp = q; }
        }
        for (int off = 32; off > 0; off >>= 1) {
            unsigned long long ob = __shfl_down(b, off);
            int op = __shfl_down(bp, off);
            if (ob > b) { b = ob; bp = op; }
        }
        unsigned long long b0 = __shfl(b, 0);
        int bp0 = __shfl(bp, 0);
        if (lane == it) { mykey = b0; kl[w][bp0] = 0ull; }
    }

    float myv = -FLT_MAX; int myj = 0;
    if (lane < TOPK && mykey != 0ull) {
        float sv = finv((unsigned)(mykey >> 32));   // exact -max(sq,0)
        myv = -sqrtf(-sv);
        myj = 8191 - (int)(mykey & 0xFFFFFFFFu);
    }
    float Mx = __shfl(myv, 0);
    float e = (lane < TOPK && mykey != 0ull) ? expf(myv - Mx) : 0.f;
    float Z = e;
    for (int off = 32; off > 0; off >>= 1) Z += __shfl_xor(Z, off);
    float s = e / Z;
    if (lane < TOPK && mykey != 0ull) {
        score_out[(size_t)r * TOPK + lane] = s;
        out[(size_t)r * N + myj] = s;    // zeros laid down by pass 2
    }
}

// ---------------------------------------------------------------------------
// FALLBACK path (workspace too small): r0 verified pipeline.
// ---------------------------------------------------------------------------
__global__ __launch_bounds__(256) void norms_kernel(
    const float* __restrict__ X1, const float* __restrict__ X2,
    float* __restrict__ nrm)
{
    int id = blockIdx.x * blockDim.x + threadIdx.x;
    if (id >= 2 * N) return;
    const float* X = (id < N) ? X1 : X2;
    int r = (id < N) ? id : id - N;
    const float4* p = (const float4*)(X + (size_t)r * D);
    float s = 0.f;
#pragma unroll
    for (int q = 0; q < D / 4; ++q) {
        float4 v = p[q];
        s += v.x * v.x + v.y * v.y + v.z * v.z + v.w * v.w;
    }
    nrm[id] = s;
}

__global__ __launch_bounds__(256, 2) void dist_kernel(
    const float* __restrict__ X1, const float* __restrict__ X2,
    const float* __restrict__ nrm, float* __restrict__ out,
    float* __restrict__ tmax, int have_tmax)
{
    __shared__ float As[D * TILE];
    __shared__ float Bs[D * TILE];

    const int t = threadIdx.x;
    const int row0 = blockIdx.y * TILE;
    const int col0 = blockIdx.x * TILE;

#pragma unroll
    for (int p = 0; p < 8; ++p) {
        int lin = p * 256 + t;
        int r   = lin >> 4;
        int d4  = (lin & 15) << 2;
        int g   = (d4 >> 2) & 7;
        int cb  = r ^ (g << 3);
        float4 a = *(const float4*)(X1 + (size_t)(row0 + r) * D + d4);
        As[(d4 + 0) * TILE + cb] = a.x;
        As[(d4 + 1) * TILE + cb] = a.y;
        As[(d4 + 2) * TILE + cb] = a.z;
        As[(d4 + 3) * TILE + cb] = a.w;
        float4 b = *(const float4*)(X2 + (size_t)(col0 + r) * D + d4);
        Bs[(d4 + 0) * TILE + cb] = b.x;
        Bs[(d4 + 1) * TILE + cb] = b.y;
        Bs[(d4 + 2) * TILE + cb] = b.z;
        Bs[(d4 + 3) * TILE + cb] = b.w;
    }
    __syncthreads();

    const int tx = t & 15;
    const int ty = t >> 4;
    float acc[8][8] = {};

#pragma unroll 8
    for (int k = 0; k < D; ++k) {
        int gk  = (k >> 2) & 7;
        int ab  = k * TILE + ((ty ^ gk) << 3);
        int bb0 = k * TILE + ((4 * tx) ^ (gk << 3));
        float4 a0 = *(const float4*)&As[ab];
        float4 a1 = *(const float4*)&As[ab + 4];
        float4 b0 = *(const float4*)&Bs[bb0];
        float4 b1 = *(const float4*)&Bs[bb0 + 64];
        float av[8] = {a0.x, a0.y, a0.z, a0.w, a1.x, a1.y, a1.z, a1.w};
        float bv[8] = {b0.x, b0.y, b0.z, b0.w, b1.x, b1.y, b1.z, b1.w};
#pragma unroll
        for (int i = 0; i < 8; ++i)
#pragma unroll
            for (int j = 0; j < 8; ++j)
                acc[i][j] += av[i] * bv[j];
    }

    float na[8], nb[8];
#pragma unroll
    for (int i = 0; i < 8; ++i) na[i] = nrm[row0 + 8 * ty + i];
#pragma unroll
    for (int q = 0; q < 4; ++q) {
        nb[q]     = nrm[N + col0 + 4 * tx + q];
        nb[4 + q] = nrm[N + col0 + 64 + 4 * tx + q];
    }

    float rmax[8];
#pragma unroll
    for (int i = 0; i < 8; ++i) rmax[i] = -FLT_MAX;

#pragma unroll
    for (int i = 0; i < 8; ++i) {
        float* po = out + (size_t)(row0 + 8 * ty + i) * N + col0 + 4 * tx;
        float4 o0, o1;
        float* f0 = (float*)&o0;
        float* f1 = (float*)&o1;
#pragma unroll
        for (int q = 0; q < 4; ++q) {
            float s0 = na[i] + nb[q] - 2.0f * acc[i][q];
            f0[q] = -fmaxf(s0, 0.0f);
            float s1 = na[i] + nb[4 + q] - 2.0f * acc[i][4 + q];
            f1[q] = -fmaxf(s1, 0.0f);
            rmax[i] = fmaxf(rmax[i], fmaxf(f0[q], f1[q]));
        }
        *(float4*)po        = o0;
        *(float4*)(po + 64) = o1;
    }

    if (have_tmax) {
#pragma unroll
        for (int i = 0; i < 8; ++i) {
            float mv = rmax[i];
            mv = fmaxf(mv, __shfl_down(mv, 8, 16));
            mv = fmaxf(mv, __shfl_down(mv, 4, 16));
            mv = fmaxf(mv, __shfl_down(mv, 2, 16));
            mv = fmaxf(mv, __shfl_down(mv, 1, 16));
            if (tx == 0)
                tmax[(size_t)(row0 + 8 * ty + i) * 64 + blockIdx.x] = mv;
        }
    }
}

__global__ __launch_bounds__(256) void topk_kernel(
    float* __restrict__ out, float* __restrict__ score_out,
    const float* __restrict__ tmax, int have_tmax)
{
    __shared__ unsigned long long candl[4][CAP];   // 32 KB
    __shared__ int scnt[4];

    const int t    = threadIdx.x;
    const int w    = t >> 6;
    const int lane = t & 63;
    const int r    = blockIdx.x * 4 + w;
    float* row = out + (size_t)r * N;
    const float4* row4 = (const float4*)row;

    float thr;
    float lm = -FLT_MAX;
    if (have_tmax) {
        float tm = tmax[(size_t)r * 64 + lane];
        unsigned km = ford(tm);
        int rk = 0;
#pragma unroll
        for (int l = 0; l < 64; ++l) {
            unsigned o = __shfl(km, l);
            rk += (o > km || (o == km && l < lane)) ? 1 : 0;
        }
        unsigned long long bm = __ballot(rk == 31);
        thr = __shfl(tm, __ffsll(bm) - 1);
    } else {
#pragma unroll 8
        for (int c = 0; c < 32; ++c) {
            float4 x = row4[c * 64 + lane];
            lm = fmaxf(lm, fmaxf(fmaxf(x.x, x.y), fmaxf(x.z, x.w)));
        }
        thr = lm;
        for (int off = 32; off > 0; off >>= 1)
            thr = fminf(thr, __shfl_xor(thr, off));
    }

    for (int attempt = 0; ; ++attempt) {
        if (lane == 0) scnt[w] = 0;
        __builtin_amdgcn_s_waitcnt(0xC07F);
        for (int c = 0; c < 32; ++c) {
            float4 x = row4[c * 64 + lane];
            float vs[4] = {x.x, x.y, x.z, x.w};
#pragma unroll
            for (int q = 0; q < 4; ++q) {
                float v = vs[q];
                lm = fmaxf(lm, v);
                if (v >= thr) {
                    int p = atomicAdd(&scnt[w], 1);
                    if (p < CAP) {
                        unsigned long long key =
                            ((unsigned long long)ford(v) << 32) |
                            (unsigned)(8191 - (4 * (c * 64 + lane) + q));
                        candl[w][p] = key;
                    }
                }
            }
        }
        __builtin_amdgcn_s_waitcnt(0xC07F);
        if (scnt[w] <= CAP || attempt == 1) break;
        unsigned kml = ford(lm);
        int rk2 = 0;
#pragma unroll
        for (int l = 0; l < 64; ++l) {
            unsigned o = __shfl(kml, l);
            rk2 += (o < kml || (o == kml && l < lane)) ? 1 : 0;
        }
        unsigned long long bm2 = __ballot(rk2 == 15);
        float t2 = __shfl(lm, __ffsll(bm2) - 1);
        thr = fmaxf(thr, t2);
    }
    const int n = min(scnt[w], CAP);

    unsigned long long mykey = 0ull;
    for (int it = 0; it < TOPK; ++it) {
        unsigned long long b = 0ull; int bp = 0;
        for (int q = lane; q < n; q += 64) {
            unsigned long long kk = candl[w][q];
            if (kk > b) { b = kk; bp = q; }
        }
        for (int off = 32; off > 0; off >>= 1) {
            unsigned long long ob = __shfl_down(b, off);
            int op = __shfl_down(bp, off);
            if (ob > b) { b = ob; bp = op; }
        }
        unsigned long long b0 = __shfl(b, 0);
        int bp0 = __shfl(bp, 0);
        if (lane == it) { mykey = b0; candl[w][bp0] = 0ull; }
    }

    float myv = 0.f; int myj = 0;
    if (lane < TOPK) {
        float sv = finv((unsigned)(mykey >> 32));
        myv = -sqrtf(-sv);
        myj = 8191 - (int)(mykey & 0xFFFFFFFFu);
    }
    float Mx = __shfl(myv, 0);
    float e = (lane < TOPK) ? expf(myv - Mx) : 0.f;
    float Z = e;
    for (int off = 32; off > 0; off >>= 1) Z += __shfl_xor(Z, off);
    float s = e / Z;
    if (lane < TOPK) score_out[(size_t)r * TOPK + lane] = s;

    const float4 zz = make_float4(0.f, 0.f, 0.f, 0.f);
#pragma unroll 8
    for (int c = 0; c < 32; ++c) ((float4*)row)[c * 64 + lane] = zz;
    __builtin_amdgcn_s_waitcnt(0x0F70);   // vmcnt(0)
    if (lane < TOPK) row[myj] = s;
}

// ---------------------------------------------------------------------------
extern "C" void kernel_launch(void* const* d_in, const int* in_sizes, int n_in,
                              void* d_out, int out_size, void* d_ws, size_t ws_size,
                              hipStream_t stream)
{
    const float* X1 = (const float*)d_in[0];
    const float* X2 = (const float*)d_in[1];
    float* out = (float*)d_out;
    float* score = out + (size_t)N * N;

    // MFMA-path workspace layout (all blocks 16B-aligned by construction):
    //   nrm  : 2N f32          (64 KB)
    //   tmax : N*64 f32        (2 MB)
    //   thr  : N f32           (32 KB)
    //   cnt  : N*64 i32        (2 MB)
    //   X1f/X2f : N*64 f16 each (1 MB each)
    //   cand : N*64*SLOT u16   (32 MB)
    char* base = (char*)d_ws;
    float* nrm  = (float*)base;
    float* tmax = nrm + 2 * N;
    float* thrv = tmax + (size_t)N * 64;
    int*   cnt  = (int*)(thrv + N);
    _Float16* X1f = (_Float16*)(cnt + (size_t)N * 64);
    _Float16* X2f = X1f + (size_t)N * D;
    unsigned short* cand = (unsigned short*)(X2f + (size_t)N * D);

    size_t need_new = (size_t)(2 * N + (size_t)N * 64 + N) * sizeof(float)
                    + (size_t)N * 64 * sizeof(int)
                    + 2 * (size_t)N * D * sizeof(_Float16)
                    + (size_t)N * 64 * SLOT * sizeof(unsigned short);
    size_t need_old = (size_t)(2 * N + (size_t)N * 64) * sizeof(float);

    if (ws_size >= need_new) {
        prep_kernel<<<(2 * N + 255) / 256, 256, 0, stream>>>(X1, X2, nrm, X1f, X2f);
        dim3 grid(N / TILE, N / TILE);   // 64 x 64
        mfma_tmax_kernel<<<grid, 256, 0, stream>>>(X1f, X2f, nrm, tmax);
        thr_kernel<<<N / 4, 256, 0, stream>>>(tmax, thrv);
        mfma_cand_kernel<<<grid, 256, 0, stream>>>(X1f, X2f, nrm, thrv, out, cand, cnt);
        exact_topk_kernel<<<N / 4, 256, 0, stream>>>(X1, X2, nrm, cand, cnt, out, score);
    } else {
        float* tmax_f = nrm + 2 * N;
        int have_tmax = (ws_size >= need_old) ? 1 : 0;
        norms_kernel<<<(2 * N + 255) / 256, 256, 0, stream>>>(X1, X2, nrm);
        dim3 grid(N / TILE, N / TILE);
        dist_kernel<<<grid, 256, 0, stream>>>(X1, X2, nrm, out, tmax_f, have_tmax);
        topk_kernel<<<N / 4, 256, 0, stream>>>(out, score, tmax_f, have_tmax);
    }
}

// Round 5
// 443.378 us; speedup vs baseline: 2.3127x; 1.0558x over previous
//
#include <hip/hip_runtime.h>
#include <math.h>
#include <float.h>
#include <limits.h>

#define N 8192
#define D 64
#define TOPK 32
#define TILE 128
#define CAP 1024      // fallback path: per-wave LDS candidate cap
#define SLOT 32       // per-(row,stripe) candidate slots (u16 cols)
#define CAPR 768      // pass-3 per-row candidate list cap
#define MARGIN 0.75f  // sound double-dip bound for fp16 sq-distance error

typedef _Float16 f16x8 __attribute__((ext_vector_type(8)));
typedef _Float16 f16x4v __attribute__((ext_vector_type(4)));
typedef __attribute__((ext_vector_type(4))) float f32x4;

// orderable-uint encoding of float: a > b  <=>  ford(a) > ford(b)
__device__ __forceinline__ unsigned ford(float f) {
    unsigned u = __float_as_uint(f);
    return u ^ ((u & 0x80000000u) ? 0xFFFFFFFFu : 0x80000000u);
}
__device__ __forceinline__ float finv(unsigned u) {
    unsigned b = (u & 0x80000000u) ? (u ^ 0x80000000u) : ~u;
    return __uint_as_float(b);
}

// ---------------------------------------------------------------------------
// Kernel 1: row norms (exact fp32) + fp16 conversion of X1, X2 (RNE).
// ---------------------------------------------------------------------------
__global__ __launch_bounds__(256) void prep_kernel(
    const float* __restrict__ X1, const float* __restrict__ X2,
    float* __restrict__ nrm,
    _Float16* __restrict__ X1f, _Float16* __restrict__ X2f)
{
    int id = blockIdx.x * blockDim.x + threadIdx.x;
    if (id >= 2 * N) return;
    const float* X = (id < N) ? X1 : X2;
    _Float16* H = (id < N) ? X1f : X2f;
    int r = (id < N) ? id : id - N;
    const float4* p = (const float4*)(X + (size_t)r * D);
    f16x4v* ph = (f16x4v*)(H + (size_t)r * D);
    float s = 0.f;
#pragma unroll
    for (int q = 0; q < D / 4; ++q) {
        float4 v = p[q];
        s += v.x * v.x + v.y * v.y + v.z * v.z + v.w * v.w;
        f16x4v h;
        h[0] = (_Float16)v.x; h[1] = (_Float16)v.y;
        h[2] = (_Float16)v.z; h[3] = (_Float16)v.w;
        ph[q] = h;
    }
    nrm[id] = s;
}

// ---------------------------------------------------------------------------
// LDS-staged MFMA core. A/B tiles (128 rows x 64 k, fp16 = 16 KB each) are
// CONTIGUOUS in global (row stride D == 64 == K-tile) -> perfectly coalesced
// 16B staging loads. XOR swizzle (row&7)<<3 f16-units (=16B granule) applied
// on BOTH write and read kills the 16-way LDA bank conflict (T2).
// Fragment read: lane holds X?f[base + sub*16 + (lane&15)][kh*32+(lane>>4)*8..+8]
// D frag: reg of lane = C[row=(lane>>4)*4+reg][col=lane&15] (verified r3/r4)
// ---------------------------------------------------------------------------
#define MFMA16F(a, b, c) __builtin_amdgcn_mfma_f32_16x16x32_f16((a), (b), (c), 0, 0, 0)

__device__ __forceinline__ void stage_tile(
    const _Float16* __restrict__ gsrc, _Float16* __restrict__ lds, int t)
{
    const f16x8* g = (const f16x8*)gsrc;
#pragma unroll
    for (int it = 0; it < 4; ++it) {
        int idx = it * 256 + t;          // 16B chunk index, 0..1023
        int row = idx >> 3;              // 8 chunks per 64-f16 row
        int co  = (idx & 7) << 3;        // f16 col offset
        int sw  = co ^ ((row & 7) << 3); // T2 swizzle, 16B granule
        *(f16x8*)&lds[row * 64 + sw] = g[idx];
    }
}

__device__ __forceinline__ void mfma_core_lds(
    const _Float16* __restrict__ Asm, const _Float16* __restrict__ Bsm,
    int wr, int wc, int lane, f32x4 acc[4][4])
{
    const int l15 = lane & 15;
    const int lg8 = (lane >> 4) * 8;

    f16x8 ah[4][2];
#pragma unroll
    for (int mt = 0; mt < 4; ++mt) {
        int row = wr * 64 + mt * 16 + l15;
        int sw0 = (lg8)      ^ ((row & 7) << 3);
        int sw1 = (32 + lg8) ^ ((row & 7) << 3);
        ah[mt][0] = *(const f16x8*)&Asm[row * 64 + sw0];
        ah[mt][1] = *(const f16x8*)&Asm[row * 64 + sw1];
    }
#pragma unroll
    for (int nt = 0; nt < 4; ++nt) {
        int row = wc * 64 + nt * 16 + l15;
        int sw0 = (lg8)      ^ ((row & 7) << 3);
        int sw1 = (32 + lg8) ^ ((row & 7) << 3);
        f16x8 b0 = *(const f16x8*)&Bsm[row * 64 + sw0];
        f16x8 b1 = *(const f16x8*)&Bsm[row * 64 + sw1];
#pragma unroll
        for (int mt = 0; mt < 4; ++mt) {
            acc[mt][nt] = MFMA16F(ah[mt][0], b0, acc[mt][nt]);
            acc[mt][nt] = MFMA16F(ah[mt][1], b1, acc[mt][nt]);
        }
    }
}

// ---------------------------------------------------------------------------
// Kernel 2: fp16 MFMA GEMM pass 1 — per-(row, 128-col stripe) max of
// v_f16 = -max(na + nb - 2*dot, 0)  -> tmax[row][stripe]  (2 MB)
// ---------------------------------------------------------------------------
__global__ __launch_bounds__(256) void mfma_tmax_kernel(
    const _Float16* __restrict__ X1f, const _Float16* __restrict__ X2f,
    const float* __restrict__ nrm, float* __restrict__ tmax)
{
    __shared__ _Float16 Asm[TILE * D];   // 16 KB
    __shared__ _Float16 Bsm[TILE * D];   // 16 KB
    __shared__ float red[128][2];

    const int t = threadIdx.x;
    const int lane = t & 63, w = t >> 6;
    const int wr = w >> 1, wc = w & 1;
    const int row0 = blockIdx.y * TILE, col0 = blockIdx.x * TILE;
    const int l15 = lane & 15, lg = lane >> 4;

    stage_tile(X1f + (size_t)row0 * D, Asm, t);
    stage_tile(X2f + (size_t)col0 * D, Bsm, t);
    __syncthreads();

    f32x4 acc[4][4];
#pragma unroll
    for (int mt = 0; mt < 4; ++mt)
#pragma unroll
        for (int nt = 0; nt < 4; ++nt)
            acc[mt][nt] = (f32x4){0.f, 0.f, 0.f, 0.f};

    mfma_core_lds(Asm, Bsm, wr, wc, lane, acc);

    float nb[4];
#pragma unroll
    for (int nt = 0; nt < 4; ++nt) nb[nt] = nrm[N + col0 + wc * 64 + nt * 16 + l15];

    float rmax[4][4];
#pragma unroll
    for (int mt = 0; mt < 4; ++mt) {
#pragma unroll
        for (int reg = 0; reg < 4; ++reg) {
            float na = nrm[row0 + wr * 64 + mt * 16 + lg * 4 + reg];
            float m = -FLT_MAX;
#pragma unroll
            for (int nt = 0; nt < 4; ++nt) {
                float v = -fmaxf(na + nb[nt] - 2.0f * acc[mt][nt][reg], 0.f);
                m = fmaxf(m, v);
            }
            rmax[mt][reg] = m;
        }
    }
    // reduce across the 16 col-lanes of each lane group (xor stays in-group)
#pragma unroll
    for (int off = 1; off < 16; off <<= 1)
#pragma unroll
        for (int mt = 0; mt < 4; ++mt)
#pragma unroll
            for (int reg = 0; reg < 4; ++reg)
                rmax[mt][reg] = fmaxf(rmax[mt][reg], __shfl_xor(rmax[mt][reg], off));

    if (l15 == 0) {
#pragma unroll
        for (int mt = 0; mt < 4; ++mt)
#pragma unroll
            for (int reg = 0; reg < 4; ++reg)
                red[wr * 64 + mt * 16 + lg * 4 + reg][wc] = rmax[mt][reg];
    }
    __syncthreads();
    if (t < 128)
        tmax[(size_t)(row0 + t) * 64 + blockIdx.x] = fmaxf(red[t][0], red[t][1]);
}

// ---------------------------------------------------------------------------
// Kernel 3: thr[row] = 32nd-largest stripe max - MARGIN.
// Sound: >=32 values have v_f16 >= T_A, so f16-rank32 >= T_A; any true
// top-32 x has v_exact(x) >= exact-rank32 >= f16-rank32 - e >= T_A - e,
// hence v_f16(x) >= T_A - 2e; MARGIN = 2e (worst-case fp16 bound).
// ---------------------------------------------------------------------------
__global__ __launch_bounds__(256) void thr_kernel(
    const float* __restrict__ tmax, float* __restrict__ thr)
{
    const int t = threadIdx.x;
    const int w = t >> 6;
    const int lane = t & 63;
    const int r = blockIdx.x * 4 + w;

    float tm = tmax[(size_t)r * 64 + lane];
    unsigned km = ford(tm);
    int rk = 0;
#pragma unroll
    for (int l = 0; l < 64; ++l) {
        unsigned o = __shfl(km, l);
        rk += (o > km || (o == km && l < lane)) ? 1 : 0;
    }
    unsigned long long bm = __ballot(rk == 31);
    float tv = __shfl(tm, __ffsll(bm) - 1);
    if (lane == 0) thr[r] = tv - MARGIN;
}

// ---------------------------------------------------------------------------
// Kernel 4: fp16 MFMA GEMM pass 2 — zero-fill the out tile (268 MB total),
// append survivors (v_f16 >= thr[row]) to deterministic per-(row,stripe)
// slots. LDS atomics only; NO global atomics.
// ---------------------------------------------------------------------------
__global__ __launch_bounds__(256) void mfma_cand_kernel(
    const _Float16* __restrict__ X1f, const _Float16* __restrict__ X2f,
    const float* __restrict__ nrm, const float* __restrict__ thr,
    float* __restrict__ out, unsigned short* __restrict__ cand,
    int* __restrict__ cnt)
{
    __shared__ _Float16 Asm[TILE * D];           // 16 KB
    __shared__ _Float16 Bsm[TILE * D];           // 16 KB
    __shared__ unsigned short lbuf[128][SLOT];   // 8 KB
    __shared__ int lcnt[128];

    const int t = threadIdx.x;
    const int lane = t & 63, w = t >> 6;
    const int wr = w >> 1, wc = w & 1;
    const int row0 = blockIdx.y * TILE, col0 = blockIdx.x * TILE;
    const int l15 = lane & 15, lg = lane >> 4;

    if (t < 128) lcnt[t] = 0;
    stage_tile(X1f + (size_t)row0 * D, Asm, t);
    stage_tile(X2f + (size_t)col0 * D, Bsm, t);

    // zero-fill this block's 128x128 out tile: stores are independent of the
    // MFMAs, so they drain under the compute.
    const float4 zz = make_float4(0.f, 0.f, 0.f, 0.f);
#pragma unroll
    for (int p = 0; p < 16; ++p) {
        int lin = p * 256 + t;
        int rr = lin >> 5;            // 0..127
        int c4 = (lin & 31) << 2;     // 0..124
        *(float4*)(out + (size_t)(row0 + rr) * N + col0 + c4) = zz;
    }
    __syncthreads();

    f32x4 acc[4][4];
#pragma unroll
    for (int mt = 0; mt < 4; ++mt)
#pragma unroll
        for (int nt = 0; nt < 4; ++nt)
            acc[mt][nt] = (f32x4){0.f, 0.f, 0.f, 0.f};

    mfma_core_lds(Asm, Bsm, wr, wc, lane, acc);

    float nb[4];
#pragma unroll
    for (int nt = 0; nt < 4; ++nt) nb[nt] = nrm[N + col0 + wc * 64 + nt * 16 + l15];

#pragma unroll
    for (int mt = 0; mt < 4; ++mt) {
#pragma unroll
        for (int reg = 0; reg < 4; ++reg) {
            int lrow = wr * 64 + mt * 16 + lg * 4 + reg;   // 0..127
            float na = nrm[row0 + lrow];
            float th = thr[row0 + lrow];
#pragma unroll
            for (int nt = 0; nt < 4; ++nt) {
                float v = -fmaxf(na + nb[nt] - 2.0f * acc[mt][nt][reg], 0.f);
                if (v >= th) {
                    int p0 = atomicAdd(&lcnt[lrow], 1);
                    if (p0 < SLOT)
                        lbuf[lrow][p0] = (unsigned short)(wc * 64 + nt * 16 + l15);
                }
            }
        }
    }
    __syncthreads();

    if (t < 128) {
        int c = lcnt[t];
        size_t sidx = (size_t)(row0 + t) * 64 + blockIdx.x;
        cnt[sidx] = c;                        // raw count (overflow detectable)
        unsigned short* cg = cand + sidx * SLOT;
        int m = min(c, SLOT);
        for (int j = 0; j < m; ++j) cg[j] = lbuf[t][j];
    }
}

// ---------------------------------------------------------------------------
// Kernel 5: one wave per row. Gather candidate cols (prefix-sum placement,
// overflow stripe -> all 128 cols: sound), recompute EXACT fp32 distances,
// exact top-32 (same key/tie-break as proven path), sqrt+softmax, scatter.
// ---------------------------------------------------------------------------
__global__ __launch_bounds__(256) void exact_topk_kernel(
    const float* __restrict__ X1, const float* __restrict__ X2,
    const float* __restrict__ nrm,
    const unsigned short* __restrict__ cand, const int* __restrict__ cnt,
    float* __restrict__ out, float* __restrict__ score_out)
{
    __shared__ float x1r[4][D];                     // 4 x 256 B
    __shared__ unsigned short lst[4][CAPR];         // 4 x 1.5 KB
    __shared__ unsigned long long kl[4][CAPR];      // 4 x 6 KB

    const int t = threadIdx.x;
    const int w = t >> 6;
    const int lane = t & 63;
    const int r = blockIdx.x * 4 + w;

    x1r[w][lane] = X1[(size_t)r * D + lane];

    int c = cnt[(size_t)r * 64 + lane];
    int eff = (c > SLOT) ? 128 : c;        // overflow: take whole stripe
    int pre = eff;
#pragma unroll
    for (int o = 1; o < 64; o <<= 1) {
        int pv = __shfl_up(pre, o);
        if (lane >= o) pre += pv;
    }
    int off0 = pre - eff;
    int M = __shfl(pre, 63);
    if (M > CAPR) M = CAPR;

    const unsigned short* cg = cand + ((size_t)r * 64 + lane) * SLOT;
    for (int j = 0; j < eff; ++j) {
        int pos = off0 + j;
        if (pos < CAPR) {
            int colloc = (c > SLOT) ? j : (int)cg[j];
            lst[w][pos] = (unsigned short)(lane * 128 + colloc);
        }
    }
    __builtin_amdgcn_s_waitcnt(0xC07F);   // lgkmcnt(0): lst + x1r visible in-wave

    float na = nrm[r];
    for (int q = lane; q < M; q += 64) {
        int col = lst[w][q];
        const float4* xr = (const float4*)(X2 + (size_t)col * D);
        float dot = 0.f;
#pragma unroll
        for (int i = 0; i < D / 4; ++i) {
            float4 xv = xr[i];
            dot += x1r[w][4 * i + 0] * xv.x + x1r[w][4 * i + 1] * xv.y
                 + x1r[w][4 * i + 2] * xv.z + x1r[w][4 * i + 3] * xv.w;
        }
        float v = -fmaxf(na + nrm[N + col] - 2.0f * dot, 0.f);
        kl[w][q] = ((unsigned long long)ford(v) << 32) | (unsigned)(8191 - col);
    }
    __builtin_amdgcn_s_waitcnt(0xC07F);

    unsigned long long mykey = 0ull;
    for (int it = 0; it < TOPK; ++it) {
        unsigned long long b = 0ull; int bp = 0;
        for (int q = lane; q < M; q += 64) {
            unsigned long long kk = kl[w][q];
            if (kk > b) { b = kk; bp = q; }
        }
        for (int off = 32; off > 0; off >>= 1) {
            unsigned long long ob = __shfl_down(b, off);
            int op = __shfl_down(bp, off);
            if (ob > b) { b = ob; bp = op; }
        }
        unsigned long long b0 = __shfl(b, 0);
        int bp0 = __shfl(bp, 0);
        if (lane == it) { mykey = b0; kl[w][bp0] = 0ull; }
    }

    float myv = -FLT_MAX; int myj = 0;
    if (lane < TOPK && mykey != 0ull) {
        float sv = finv((unsigned)(mykey >> 32));   // exact -max(sq,0)
        myv = -sqrtf(-sv);
        myj = 8191 - (int)(mykey & 0xFFFFFFFFu);
    }
    float Mx = __shfl(myv, 0);
    float e = (lane < TOPK && mykey != 0ull) ? expf(myv - Mx) : 0.f;
    float Z = e;
    for (int off = 32; off > 0; off >>= 1) Z += __shfl_xor(Z, off);
    float s = e / Z;
    if (lane < TOPK && mykey != 0ull) {
        score_out[(size_t)r * TOPK + lane] = s;
        out[(size_t)r * N + myj] = s;    // zeros laid down by pass 2
    }
}

// ---------------------------------------------------------------------------
// FALLBACK path (workspace too small): r0 verified pipeline.
// ---------------------------------------------------------------------------
__global__ __launch_bounds__(256) void norms_kernel(
    const float* __restrict__ X1, const float* __restrict__ X2,
    float* __restrict__ nrm)
{
    int id = blockIdx.x * blockDim.x + threadIdx.x;
    if (id >= 2 * N) return;
    const float* X = (id < N) ? X1 : X2;
    int r = (id < N) ? id : id - N;
    const float4* p = (const float4*)(X + (size_t)r * D);
    float s = 0.f;
#pragma unroll
    for (int q = 0; q < D / 4; ++q) {
        float4 v = p[q];
        s += v.x * v.x + v.y * v.y + v.z * v.z + v.w * v.w;
    }
    nrm[id] = s;
}

__global__ __launch_bounds__(256, 2) void dist_kernel(
    const float* __restrict__ X1, const float* __restrict__ X2,
    const float* __restrict__ nrm, float* __restrict__ out,
    float* __restrict__ tmax, int have_tmax)
{
    __shared__ float As[D * TILE];
    __shared__ float Bs[D * TILE];

    const int t = threadIdx.x;
    const int row0 = blockIdx.y * TILE;
    const int col0 = blockIdx.x * TILE;

#pragma unroll
    for (int p = 0; p < 8; ++p) {
        int lin = p * 256 + t;
        int r   = lin >> 4;
        int d4  = (lin & 15) << 2;
        int g   = (d4 >> 2) & 7;
        int cb  = r ^ (g << 3);
        float4 a = *(const float4*)(X1 + (size_t)(row0 + r) * D + d4);
        As[(d4 + 0) * TILE + cb] = a.x;
        As[(d4 + 1) * TILE + cb] = a.y;
        As[(d4 + 2) * TILE + cb] = a.z;
        As[(d4 + 3) * TILE + cb] = a.w;
        float4 b = *(const float4*)(X2 + (size_t)(col0 + r) * D + d4);
        Bs[(d4 + 0) * TILE + cb] = b.x;
        Bs[(d4 + 1) * TILE + cb] = b.y;
        Bs[(d4 + 2) * TILE + cb] = b.z;
        Bs[(d4 + 3) * TILE + cb] = b.w;
    }
    __syncthreads();

    const int tx = t & 15;
    const int ty = t >> 4;
    float acc[8][8] = {};

#pragma unroll 8
    for (int k = 0; k < D; ++k) {
        int gk  = (k >> 2) & 7;
        int ab  = k * TILE + ((ty ^ gk) << 3);
        int bb0 = k * TILE + ((4 * tx) ^ (gk << 3));
        float4 a0 = *(const float4*)&As[ab];
        float4 a1 = *(const float4*)&As[ab + 4];
        float4 b0 = *(const float4*)&Bs[bb0];
        float4 b1 = *(const float4*)&Bs[bb0 + 64];
        float av[8] = {a0.x, a0.y, a0.z, a0.w, a1.x, a1.y, a1.z, a1.w};
        float bv[8] = {b0.x, b0.y, b0.z, b0.w, b1.x, b1.y, b1.z, b1.w};
#pragma unroll
        for (int i = 0; i < 8; ++i)
#pragma unroll
            for (int j = 0; j < 8; ++j)
                acc[i][j] += av[i] * bv[j];
    }

    float na[8], nb[8];
#pragma unroll
    for (int i = 0; i < 8; ++i) na[i] = nrm[row0 + 8 * ty + i];
#pragma unroll
    for (int q = 0; q < 4; ++q) {
        nb[q]     = nrm[N + col0 + 4 * tx + q];
        nb[4 + q] = nrm[N + col0 + 64 + 4 * tx + q];
    }

    float rmax[8];
#pragma unroll
    for (int i = 0; i < 8; ++i) rmax[i] = -FLT_MAX;

#pragma unroll
    for (int i = 0; i < 8; ++i) {
        float* po = out + (size_t)(row0 + 8 * ty + i) * N + col0 + 4 * tx;
        float4 o0, o1;
        float* f0 = (float*)&o0;
        float* f1 = (float*)&o1;
#pragma unroll
        for (int q = 0; q < 4; ++q) {
            float s0 = na[i] + nb[q] - 2.0f * acc[i][q];
            f0[q] = -fmaxf(s0, 0.0f);
            float s1 = na[i] + nb[4 + q] - 2.0f * acc[i][4 + q];
            f1[q] = -fmaxf(s1, 0.0f);
            rmax[i] = fmaxf(rmax[i], fmaxf(f0[q], f1[q]));
        }
        *(float4*)po        = o0;
        *(float4*)(po + 64) = o1;
    }

    if (have_tmax) {
#pragma unroll
        for (int i = 0; i < 8; ++i) {
            float mv = rmax[i];
            mv = fmaxf(mv, __shfl_down(mv, 8, 16));
            mv = fmaxf(mv, __shfl_down(mv, 4, 16));
            mv = fmaxf(mv, __shfl_down(mv, 2, 16));
            mv = fmaxf(mv, __shfl_down(mv, 1, 16));
            if (tx == 0)
                tmax[(size_t)(row0 + 8 * ty + i) * 64 + blockIdx.x] = mv;
        }
    }
}

__global__ __launch_bounds__(256) void topk_kernel(
    float* __restrict__ out, float* __restrict__ score_out,
    const float* __restrict__ tmax, int have_tmax)
{
    __shared__ unsigned long long candl[4][CAP];   // 32 KB
    __shared__ int scnt[4];

    const int t    = threadIdx.x;
    const int w    = t >> 6;
    const int lane = t & 63;
    const int r    = blockIdx.x * 4 + w;
    float* row = out + (size_t)r * N;
    const float4* row4 = (const float4*)row;

    float thr;
    float lm = -FLT_MAX;
    if (have_tmax) {
        float tm = tmax[(size_t)r * 64 + lane];
        unsigned km = ford(tm);
        int rk = 0;
#pragma unroll
        for (int l = 0; l < 64; ++l) {
            unsigned o = __shfl(km, l);
            rk += (o > km || (o == km && l < lane)) ? 1 : 0;
        }
        unsigned long long bm = __ballot(rk == 31);
        thr = __shfl(tm, __ffsll(bm) - 1);
    } else {
#pragma unroll 8
        for (int c = 0; c < 32; ++c) {
            float4 x = row4[c * 64 + lane];
            lm = fmaxf(lm, fmaxf(fmaxf(x.x, x.y), fmaxf(x.z, x.w)));
        }
        thr = lm;
        for (int off = 32; off > 0; off >>= 1)
            thr = fminf(thr, __shfl_xor(thr, off));
    }

    for (int attempt = 0; ; ++attempt) {
        if (lane == 0) scnt[w] = 0;
        __builtin_amdgcn_s_waitcnt(0xC07F);
        for (int c = 0; c < 32; ++c) {
            float4 x = row4[c * 64 + lane];
            float vs[4] = {x.x, x.y, x.z, x.w};
#pragma unroll
            for (int q = 0; q < 4; ++q) {
                float v = vs[q];
                lm = fmaxf(lm, v);
                if (v >= thr) {
                    int p = atomicAdd(&scnt[w], 1);
                    if (p < CAP) {
                        unsigned long long key =
                            ((unsigned long long)ford(v) << 32) |
                            (unsigned)(8191 - (4 * (c * 64 + lane) + q));
                        candl[w][p] = key;
                    }
                }
            }
        }
        __builtin_amdgcn_s_waitcnt(0xC07F);
        if (scnt[w] <= CAP || attempt == 1) break;
        unsigned kml = ford(lm);
        int rk2 = 0;
#pragma unroll
        for (int l = 0; l < 64; ++l) {
            unsigned o = __shfl(kml, l);
            rk2 += (o < kml || (o == kml && l < lane)) ? 1 : 0;
        }
        unsigned long long bm2 = __ballot(rk2 == 15);
        float t2 = __shfl(lm, __ffsll(bm2) - 1);
        thr = fmaxf(thr, t2);
    }
    const int n = min(scnt[w], CAP);

    unsigned long long mykey = 0ull;
    for (int it = 0; it < TOPK; ++it) {
        unsigned long long b = 0ull; int bp = 0;
        for (int q = lane; q < n; q += 64) {
            unsigned long long kk = candl[w][q];
            if (kk > b) { b = kk; bp = q; }
        }
        for (int off = 32; off > 0; off >>= 1) {
            unsigned long long ob = __shfl_down(b, off);
            int op = __shfl_down(bp, off);
            if (ob > b) { b = ob; bp = op; }
        }
        unsigned long long b0 = __shfl(b, 0);
        int bp0 = __shfl(bp, 0);
        if (lane == it) { mykey = b0; candl[w][bp0] = 0ull; }
    }

    float myv = 0.f; int myj = 0;
    if (lane < TOPK) {
        float sv = finv((unsigned)(mykey >> 32));
        myv = -sqrtf(-sv);
        myj = 8191 - (int)(mykey & 0xFFFFFFFFu);
    }
    float Mx = __shfl(myv, 0);
    float e = (lane < TOPK) ? expf(myv - Mx) : 0.f;
    float Z = e;
    for (int off = 32; off > 0; off >>= 1) Z += __shfl_xor(Z, off);
    float s = e / Z;
    if (lane < TOPK) score_out[(size_t)r * TOPK + lane] = s;

    const float4 zz = make_float4(0.f, 0.f, 0.f, 0.f);
#pragma unroll 8
    for (int c = 0; c < 32; ++c) ((float4*)row)[c * 64 + lane] = zz;
    __builtin_amdgcn_s_waitcnt(0x0F70);   // vmcnt(0)
    if (lane < TOPK) row[myj] = s;
}

// ---------------------------------------------------------------------------
extern "C" void kernel_launch(void* const* d_in, const int* in_sizes, int n_in,
                              void* d_out, int out_size, void* d_ws, size_t ws_size,
                              hipStream_t stream)
{
    const float* X1 = (const float*)d_in[0];
    const float* X2 = (const float*)d_in[1];
    float* out = (float*)d_out;
    float* score = out + (size_t)N * N;

    // MFMA-path workspace layout (all blocks 16B-aligned by construction):
    //   nrm  : 2N f32          (64 KB)
    //   tmax : N*64 f32        (2 MB)
    //   thr  : N f32           (32 KB)
    //   cnt  : N*64 i32        (2 MB)
    //   X1f/X2f : N*64 f16 each (1 MB each)
    //   cand : N*64*SLOT u16   (32 MB)
    char* base = (char*)d_ws;
    float* nrm  = (float*)base;
    float* tmax = nrm + 2 * N;
    float* thrv = tmax + (size_t)N * 64;
    int*   cnt  = (int*)(thrv + N);
    _Float16* X1f = (_Float16*)(cnt + (size_t)N * 64);
    _Float16* X2f = X1f + (size_t)N * D;
    unsigned short* cand = (unsigned short*)(X2f + (size_t)N * D);

    size_t need_new = (size_t)(2 * N + (size_t)N * 64 + N) * sizeof(float)
                    + (size_t)N * 64 * sizeof(int)
                    + 2 * (size_t)N * D * sizeof(_Float16)
                    + (size_t)N * 64 * SLOT * sizeof(unsigned short);
    size_t need_old = (size_t)(2 * N + (size_t)N * 64) * sizeof(float);

    if (ws_size >= need_new) {
        prep_kernel<<<(2 * N + 255) / 256, 256, 0, stream>>>(X1, X2, nrm, X1f, X2f);
        dim3 grid(N / TILE, N / TILE);   // 64 x 64
        mfma_tmax_kernel<<<grid, 256, 0, stream>>>(X1f, X2f, nrm, tmax);
        thr_kernel<<<N / 4, 256, 0, stream>>>(tmax, thrv);
        mfma_cand_kernel<<<grid, 256, 0, stream>>>(X1f, X2f, nrm, thrv, out, cand, cnt);
        exact_topk_kernel<<<N / 4, 256, 0, stream>>>(X1, X2, nrm, cand, cnt, out, score);
    } else {
        float* tmax_f = nrm + 2 * N;
        int have_tmax = (ws_size >= need_old) ? 1 : 0;
        norms_kernel<<<(2 * N + 255) / 256, 256, 0, stream>>>(X1, X2, nrm);
        dim3 grid(N / TILE, N / TILE);
        dist_kernel<<<grid, 256, 0, stream>>>(X1, X2, nrm, out, tmax_f, have_tmax);
        topk_kernel<<<N / 4, 256, 0, stream>>>(out, score, tmax_f, have_tmax);
    }
}